// Round 1
// baseline (3688.449 us; speedup 1.0000x reference)
//
#include <hip/hip_runtime.h>
#include <math.h>

#define BB 8
#define TT 512
#define DD 256
#define DIM 512
#define KW 4
#define MM 2
#define HH 4
#define HDIM 64
#define LL 2
#define VV 272

__device__ __forceinline__ float sigf(float x){ return 1.f/(1.f+__expf(-x)); }
__device__ __forceinline__ float siluf(float x){ return x/(1.f+__expf(-x)); }

// ---------------- embedding gather ----------------
__global__ void k_embed(const int* __restrict__ ids, const float* __restrict__ emb,
                        float* __restrict__ x){
  int row = blockIdx.x;            // b*T+t
  int d = threadIdx.x;             // 256
  x[row*DD + d] = emb[ids[row]*DD + d];
}

// ---------------- rmsnorm (row of 256), 1 wave/row ----------------
__global__ void k_rmsnorm(const float* __restrict__ in, const float* __restrict__ w,
                          float* __restrict__ out){
  int row = blockIdx.x;
  int l = threadIdx.x;             // 64
  float4 v = *(const float4*)&in[row*DD + l*4];
  float ss = v.x*v.x + v.y*v.y + v.z*v.z + v.w*v.w;
  #pragma unroll
  for (int o = 32; o > 0; o >>= 1) ss += __shfl_xor(ss, o, 64);
  float sc = rsqrtf(ss*(1.f/DD) + 1e-6f);
  float4 wv = *(const float4*)&w[l*4];
  float4 r;
  r.x = v.x*sc*wv.x; r.y = v.y*sc*wv.y; r.z = v.z*sc*wv.z; r.w = v.w*sc*wv.w;
  *(float4*)&out[row*DD + l*4] = r;
}

// ---------------- generic f32 GEMM: C[4096,N] = A[4096,K] @ B ----------------
// BT=false: B is (K,N) row-major.  BT=true: B is (N,K) row-major (i.e. C = A @ B^T).
template<bool BT>
__global__ void __launch_bounds__(256) k_gemm(const float* __restrict__ A,
                                              const float* __restrict__ B,
                                              float* __restrict__ C, int N, int K){
  __shared__ float as[16][65];
  __shared__ float bs[16][65];
  int tid = threadIdx.x;
  int tx = tid & 15, ty = tid >> 4;
  int m0 = blockIdx.y * 64, n0 = blockIdx.x * 64;
  float acc[4][4] = {};
  for (int k0 = 0; k0 < K; k0 += 16){
    #pragma unroll
    for (int i = tid; i < 1024; i += 256){
      int mm = i >> 4, kk = i & 15;
      as[kk][mm] = A[(m0+mm)*K + k0 + kk];
    }
    if (!BT){
      #pragma unroll
      for (int i = tid; i < 1024; i += 256){
        int kk = i >> 6, nn = i & 63;
        int n = n0 + nn;
        bs[kk][nn] = (n < N) ? B[(size_t)(k0+kk)*N + n] : 0.f;
      }
    } else {
      #pragma unroll
      for (int i = tid; i < 1024; i += 256){
        int nn = i >> 4, kk = i & 15;
        int n = n0 + nn;
        bs[kk][nn] = (n < N) ? B[(size_t)n*K + k0 + kk] : 0.f;
      }
    }
    __syncthreads();
    #pragma unroll
    for (int kk = 0; kk < 16; ++kk){
      float a[4], bv[4];
      #pragma unroll
      for (int j = 0; j < 4; ++j){ a[j] = as[kk][ty*4+j]; bv[j] = bs[kk][tx*4+j]; }
      #pragma unroll
      for (int i = 0; i < 4; ++i)
        #pragma unroll
        for (int j = 0; j < 4; ++j) acc[i][j] = fmaf(a[i], bv[j], acc[i][j]);
    }
    __syncthreads();
  }
  int n = n0 + tx*4;
  if (n < N){
    #pragma unroll
    for (int i = 0; i < 4; ++i){
      float4 r; r.x = acc[i][0]; r.y = acc[i][1]; r.z = acc[i][2]; r.w = acc[i][3];
      *(float4*)&C[(size_t)(m0+ty*4+i)*N + n] = r;
    }
  }
}

// ---------------- causal depthwise conv + silu gating (in-place on g) --------
__global__ void k_conv(const float* __restrict__ u, const float* __restrict__ g,
                       const float* __restrict__ cw, const float* __restrict__ cb,
                       float* __restrict__ hh){
  int idx = blockIdx.x*256 + threadIdx.x;  // over B*T*DIM
  int c  = idx % DIM;
  int bt = idx / DIM;
  int t  = bt % TT;
  float acc = cb[c];
  #pragma unroll
  for (int j = 0; j < KW; ++j){
    int dt_ = j - (KW-1);
    if (t + dt_ >= 0) acc = fmaf(u[(bt + dt_)*DIM + c], cw[c*KW + j], acc);
  }
  float h = siluf(acc);
  hh[idx] = siluf(g[idx]) * h;
}

// ---------------- pack small projection weights into (D, 28) ----------------
// cols: 0..3 gate(h) | 4..11 beta(m,h) | 12..19 alpha(m,h) | 20..27 blend(h*2+m)
__global__ void k_pack(const float* __restrict__ Wg, const float* __restrict__ Wb,
                       const float* __restrict__ Wa, const float* __restrict__ Wbl,
                       float* __restrict__ Wp){
  int d = blockIdx.x;     // 256
  int j = threadIdx.x;    // 32 (28 used)
  if (j >= 28) return;
  float v;
  if (j < 4)        v = Wg[d*HH + j];
  else if (j < 12){ int m=(j-4)>>2, h=(j-4)&3;  v = Wb[(m*DD + d)*HH + h]; }
  else if (j < 20){ int m=(j-12)>>2, h=(j-12)&3; v = Wa[(m*DD + d)*HH + h]; }
  else              v = Wbl[d*(HH*MM) + (j-20)];
  Wp[d*28 + j] = v;
}

// ---------------- rk normalization: unit-norm per (b,t,h) over 64 ----------
__global__ void k_rk(const float* __restrict__ y, float* __restrict__ rkb){
  int blk = blockIdx.x;          // B*T*H
  int lane = threadIdx.x;        // 64
  int row = blk >> 2, h = blk & 3;
  float v = y[row*DD + h*HDIM + lane];
  float ss = v*v;
  #pragma unroll
  for (int o = 32; o > 0; o >>= 1) ss += __shfl_xor(ss, o, 64);
  float nrm = fmaxf(sqrtf(ss), 1e-12f);
  rkb[row*DD + h*HDIM + lane] = v / nrm;
}

// ---------------- sequential delta-memory scan ----------------
// grid: B*H blocks; block: 128 threads = 2 waves (m = wave id), lane k owns S[:,k].
__global__ void __launch_bounds__(128) k_scan(const float* __restrict__ vals,
                                              const float* __restrict__ rkb,
                                              const float* __restrict__ proj,
                                              const float* __restrict__ A_log,
                                              const float* __restrict__ dt_bias,
                                              float* __restrict__ obuf){
  int b = blockIdx.x >> 2, h = blockIdx.x & 3;
  int m = threadIdx.x >> 6, k = threadIdx.x & 63;
  __shared__ float rs[2][64];
  __shared__ float oc[128];
  float S[64];
  #pragma unroll
  for (int d = 0; d < 64; ++d) S[d] = 0.f;
  float Al = __expf(A_log[m*HH + h]);
  float db = dt_bias[m*HH + h];
  if (threadIdx.x < 64) rs[0][threadIdx.x] = 0.f;
  __syncthreads();
  int cur = 1;
  for (int t = 0; t < TT; ++t){
    int row = b*TT + t;
    if (m == 0) rs[cur][k] = rkb[row*DD + h*HDIM + k];
    const float* p = proj + row*28;
    float g   = p[h];
    float btl = p[4  + m*4 + h];
    float alr = p[12 + m*4 + h];
    float l0  = p[20 + h*2];
    float l1  = p[20 + h*2 + 1];
    float v   = vals[(size_t)(row*MM + m)*DD + h*HDIM + k];
    __syncthreads();
    // scalars
    float sp = alr + db;
    sp = (sp > 15.f) ? sp : log1pf(__expf(sp));
    float dc = __expf(-Al * sp);
    float bt = sigf(btl);
    float mx = fmaxf(l0, l1);
    float e0 = __expf(l0-mx), e1 = __expf(l1-mx);
    float bl = ((m == 0) ? e0 : e1) / (e0 + e1);
    const float* prv = rs[cur^1];
    const float* cc  = rs[cur];
    // pred = dc * <S_old, wk>
    float p0=0.f,p1=0.f,p2=0.f,p3=0.f;
    #pragma unroll
    for (int d4 = 0; d4 < 16; ++d4){
      float4 r = *(const float4*)&prv[d4*4];
      float4 w;
      if (m == 0) w = r; else { w.x = -r.y; w.y = r.x; w.z = -r.w; w.w = r.z; }
      p0 = fmaf(S[d4*4+0], w.x, p0);
      p1 = fmaf(S[d4*4+1], w.y, p1);
      p2 = fmaf(S[d4*4+2], w.z, p2);
      p3 = fmaf(S[d4*4+3], w.w, p3);
    }
    float pred = ((p0+p1)+(p2+p3)) * dc;
    float err = (v - pred) * bt;
    // S = dc*S + wk*err ; read = <S_new, rk>
    float r0=0.f,r1=0.f,r2=0.f,r3=0.f;
    #pragma unroll
    for (int d4 = 0; d4 < 16; ++d4){
      float4 rp = *(const float4*)&prv[d4*4];
      float4 rc = *(const float4*)&cc[d4*4];
      float4 w, rr;
      if (m == 0){ w = rp; rr = rc; }
      else { w.x=-rp.y; w.y=rp.x; w.z=-rp.w; w.w=rp.z; rr.x=-rc.y; rr.y=rc.x; rr.z=-rc.w; rr.w=rc.z; }
      S[d4*4+0] = fmaf(S[d4*4+0], dc, w.x*err);
      S[d4*4+1] = fmaf(S[d4*4+1], dc, w.y*err);
      S[d4*4+2] = fmaf(S[d4*4+2], dc, w.z*err);
      S[d4*4+3] = fmaf(S[d4*4+3], dc, w.w*err);
      r0 = fmaf(S[d4*4+0], rr.x, r0);
      r1 = fmaf(S[d4*4+1], rr.y, r1);
      r2 = fmaf(S[d4*4+2], rr.z, r2);
      r3 = fmaf(S[d4*4+3], rr.w, r3);
    }
    float rd = (r0+r1)+(r2+r3);
    oc[threadIdx.x] = bl * rd;
    __syncthreads();
    if (m == 0) obuf[row*DD + h*HDIM + k] = g * (oc[k] + oc[64+k]);
    cur ^= 1;
  }
}

// ---------------- residual: x += y + z ----------------
__global__ void k_resid(float* __restrict__ x, const float* __restrict__ y,
                        const float* __restrict__ z){
  int i = blockIdx.x*256 + threadIdx.x;
  float4* x4 = (float4*)x;
  const float4* y4 = (const float4*)y;
  const float4* z4 = (const float4*)z;
  float4 a = x4[i], bq = y4[i], c = z4[i];
  a.x += bq.x + c.x; a.y += bq.y + c.y; a.z += bq.z + c.z; a.w += bq.w + c.w;
  x4[i] = a;
}

extern "C" void kernel_launch(void* const* d_in, const int* in_sizes, int n_in,
                              void* d_out, int out_size, void* d_ws, size_t ws_size,
                              hipStream_t stream){
  const int*   ids   = (const int*)d_in[0];
  const float* emb   = (const float*)d_in[1];
  const float* normw = (const float*)d_in[2];
  const float* Wup   = (const float*)d_in[3];
  const float* Wgate = (const float*)d_in[4];
  const float* Wdown = (const float*)d_in[5];
  const float* convw = (const float*)d_in[6];
  const float* convb = (const float*)d_in[7];
  const float* Wv    = (const float*)d_in[8];
  const float* Wg    = (const float*)d_in[9];
  const float* Wb    = (const float*)d_in[10];
  const float* Wa    = (const float*)d_in[11];
  const float* A_log = (const float*)d_in[12];
  const float* dtb   = (const float*)d_in[13];
  const float* Wbl   = (const float*)d_in[14];
  const float* Wout  = (const float*)d_in[15];
  const float* fnw   = (const float*)d_in[16];
  float* out = (float*)d_out;

  const int ROWS = BB*TT;              // 4096
  const size_t MEG = 1u << 20;         // 1,048,576 floats
  float* ws   = (float*)d_ws;
  float* x    = ws;                    // 1M
  float* nx   = x    + MEG;            // 1M
  float* big1 = nx   + MEG;            // 2M : u, then vals
  float* big2 = big1 + 2*MEG;          // 2M : g/hh, then obuf+z
  float* y    = big2 + 2*MEG;          // 1M
  float* proj = y    + MEG;            // 4096*28
  float* rkb  = proj + (1u<<17);       // 1M
  float* Wp   = rkb  + MEG;            // 256*28

  k_embed<<<ROWS, DD, 0, stream>>>(ids, emb, x);

  for (int l = 0; l < LL; ++l){
    k_rmsnorm<<<ROWS, 64, 0, stream>>>(x, normw + l*DD, nx);
    float* u = big1; float* g = big2;
    k_gemm<false><<<dim3(DIM/64, ROWS/64), 256, 0, stream>>>(nx, Wup + (size_t)l*DD*DIM, u, DIM, DD);
    k_gemm<false><<<dim3(DIM/64, ROWS/64), 256, 0, stream>>>(nx, Wgate + (size_t)l*DD*DIM, g, DIM, DD);
    k_conv<<<(ROWS*DIM)/256, 256, 0, stream>>>(u, g, convw + l*DIM*KW, convb + l*DIM, g);
    k_gemm<false><<<dim3(DD/64, ROWS/64), 256, 0, stream>>>(g, Wdown + (size_t)l*DIM*DD, y, DD, DIM);
    float* vals = big1;
    k_gemm<false><<<dim3((MM*DD)/64, ROWS/64), 256, 0, stream>>>(y, Wv + (size_t)l*DD*MM*DD, vals, MM*DD, DD);
    k_pack<<<DD, 32, 0, stream>>>(Wg + l*DD*HH, Wb + l*MM*DD*HH, Wa + l*MM*DD*HH,
                                  Wbl + l*DD*HH*MM, Wp);
    k_gemm<false><<<dim3(1, ROWS/64), 256, 0, stream>>>(y, Wp, proj, 28, DD);
    k_rk<<<ROWS*HH, 64, 0, stream>>>(y, rkb);
    float* obuf = big2; float* z = big2 + MEG;
    k_scan<<<BB*HH, 128, 0, stream>>>(vals, rkb, proj, A_log + l*MM*HH, dtb + l*MM*HH, obuf);
    k_gemm<false><<<dim3(DD/64, ROWS/64), 256, 0, stream>>>(obuf, Wout + (size_t)l*DD*DD, z, DD, DD);
    k_resid<<<(ROWS*DD)/1024, 256, 0, stream>>>(x, y, z);
  }

  k_rmsnorm<<<ROWS, 64, 0, stream>>>(x, fnw, nx);
  k_gemm<true><<<dim3((VV+63)/64, ROWS/64), 256, 0, stream>>>(nx, emb, out, VV, DD);
}

// Round 2
// 1683.364 us; speedup vs baseline: 2.1911x; 2.1911x over previous
//
#include <hip/hip_runtime.h>
#include <math.h>

#define BB 8
#define TT 512
#define DD 256
#define DIM 512
#define KW 4
#define MM 2
#define HH 4
#define HDIM 64
#define LL 2
#define VV 272

__device__ __forceinline__ float sigf(float x){ return 1.f/(1.f+__expf(-x)); }
__device__ __forceinline__ float siluf(float x){ return x/(1.f+__expf(-x)); }

// ---------------- embedding gather ----------------
__global__ void k_embed(const int* __restrict__ ids, const float* __restrict__ emb,
                        float* __restrict__ x){
  int row = blockIdx.x;            // b*T+t
  int d = threadIdx.x;             // 256
  x[row*DD + d] = emb[ids[row]*DD + d];
}

// ---------------- rmsnorm (row of 256), 1 wave/row ----------------
__global__ void k_rmsnorm(const float* __restrict__ in, const float* __restrict__ w,
                          float* __restrict__ out){
  int row = blockIdx.x;
  int l = threadIdx.x;             // 64
  float4 v = *(const float4*)&in[row*DD + l*4];
  float ss = v.x*v.x + v.y*v.y + v.z*v.z + v.w*v.w;
  #pragma unroll
  for (int o = 32; o > 0; o >>= 1) ss += __shfl_xor(ss, o, 64);
  float sc = rsqrtf(ss*(1.f/DD) + 1e-6f);
  float4 wv = *(const float4*)&w[l*4];
  float4 r;
  r.x = v.x*sc*wv.x; r.y = v.y*sc*wv.y; r.z = v.z*sc*wv.z; r.w = v.w*sc*wv.w;
  *(float4*)&out[row*DD + l*4] = r;
}

// ---------------- generic f32 GEMM: C[4096,N] = A[4096,K] @ B ----------------
// BT=false: B is (K,N) row-major.  BT=true: B is (N,K) row-major (i.e. C = A @ B^T).
template<bool BT>
__global__ void __launch_bounds__(256) k_gemm(const float* __restrict__ A,
                                              const float* __restrict__ B,
                                              float* __restrict__ C, int N, int K){
  __shared__ float as[16][65];
  __shared__ float bs[16][65];
  int tid = threadIdx.x;
  int tx = tid & 15, ty = tid >> 4;
  int m0 = blockIdx.y * 64, n0 = blockIdx.x * 64;
  float acc[4][4] = {};
  for (int k0 = 0; k0 < K; k0 += 16){
    #pragma unroll
    for (int i = tid; i < 1024; i += 256){
      int mm = i >> 4, kk = i & 15;
      as[kk][mm] = A[(m0+mm)*K + k0 + kk];
    }
    if (!BT){
      #pragma unroll
      for (int i = tid; i < 1024; i += 256){
        int kk = i >> 6, nn = i & 63;
        int n = n0 + nn;
        bs[kk][nn] = (n < N) ? B[(size_t)(k0+kk)*N + n] : 0.f;
      }
    } else {
      #pragma unroll
      for (int i = tid; i < 1024; i += 256){
        int nn = i >> 4, kk = i & 15;
        int n = n0 + nn;
        bs[kk][nn] = (n < N) ? B[(size_t)n*K + k0 + kk] : 0.f;
      }
    }
    __syncthreads();
    #pragma unroll
    for (int kk = 0; kk < 16; ++kk){
      float a[4], bv[4];
      #pragma unroll
      for (int j = 0; j < 4; ++j){ a[j] = as[kk][ty*4+j]; bv[j] = bs[kk][tx*4+j]; }
      #pragma unroll
      for (int i = 0; i < 4; ++i)
        #pragma unroll
        for (int j = 0; j < 4; ++j) acc[i][j] = fmaf(a[i], bv[j], acc[i][j]);
    }
    __syncthreads();
  }
  int n = n0 + tx*4;
  if (n < N){
    #pragma unroll
    for (int i = 0; i < 4; ++i){
      float4 r; r.x = acc[i][0]; r.y = acc[i][1]; r.z = acc[i][2]; r.w = acc[i][3];
      *(float4*)&C[(size_t)(m0+ty*4+i)*N + n] = r;
    }
  }
}

// ---------------- causal depthwise conv + silu gating --------
__global__ void k_conv(const float* __restrict__ u, const float* __restrict__ g,
                       const float* __restrict__ cw, const float* __restrict__ cb,
                       float* __restrict__ hh){
  int idx = blockIdx.x*256 + threadIdx.x;  // over B*T*DIM
  int c  = idx % DIM;
  int bt = idx / DIM;
  int t  = bt % TT;
  float acc = cb[c];
  #pragma unroll
  for (int j = 0; j < KW; ++j){
    int dt_ = j - (KW-1);
    if (t + dt_ >= 0) acc = fmaf(u[(bt + dt_)*DIM + c], cw[c*KW + j], acc);
  }
  float h = siluf(acc);
  hh[idx] = siluf(g[idx]) * h;
}

// ---------------- pack small projection weights into (D, 28) ----------------
// cols: 0..3 gate(h) | 4..11 beta(m,h) | 12..19 alpha(m,h) | 20..27 blend(h*2+m)
__global__ void k_pack(const float* __restrict__ Wg, const float* __restrict__ Wb,
                       const float* __restrict__ Wa, const float* __restrict__ Wbl,
                       float* __restrict__ Wp){
  int d = blockIdx.x;     // 256
  int j = threadIdx.x;    // 32 (28 used)
  if (j >= 28) return;
  float v;
  if (j < 4)        v = Wg[d*HH + j];
  else if (j < 12){ int m=(j-4)>>2, h=(j-4)&3;  v = Wb[(m*DD + d)*HH + h]; }
  else if (j < 20){ int m=(j-12)>>2, h=(j-12)&3; v = Wa[(m*DD + d)*HH + h]; }
  else              v = Wbl[d*(HH*MM) + (j-20)];
  Wp[d*28 + j] = v;
}

// ---------------- rk normalization: unit-norm per (b,t,h) over 64 ----------
__global__ void k_rk(const float* __restrict__ y, float* __restrict__ rkb){
  int blk = blockIdx.x;          // B*T*H
  int lane = threadIdx.x;        // 64
  int row = blk >> 2, h = blk & 3;
  float v = y[row*DD + h*HDIM + lane];
  float ss = v*v;
  #pragma unroll
  for (int o = 32; o > 0; o >>= 1) ss += __shfl_xor(ss, o, 64);
  float nrm = fmaxf(sqrtf(ss), 1e-12f);
  rkb[row*DD + h*HDIM + lane] = v / nrm;
}

// ---------------- sequential delta-memory scan, barrier-free ----------------
// grid: B*H*M blocks of 128 threads (2 independent waves).
// wave w covers k in [w*32, w*32+32); lane = 2*kk_local + half, half owns
// d in [half*32, half*32+32). Reductions over d finish with shfl_xor(.,1).
// wk(t) = rk(t-1) kept in registers (rkA/rkB double buffer, unroll-by-2).
// Depth-1 prefetch of v/rk/proj. No __syncthreads anywhere.
// Each (m) wavegroup writes bl*g*read to its own partial buffer; k_comb adds.

#define STEP(T_, PH, RCUR, RPRV) { \
  const int row = rowbase + (T_); \
  rs_my[PH][l] = rk_pf; \
  __builtin_amdgcn_wave_barrier(); \
  const float v = v_pf; \
  const float gv = g_pf, btl = bt_pf, alr = al_pf, q0 = l0_pf, q1 = l1_pf; \
  { const int tn = ((T_)+1 < TT) ? (T_)+1 : (T_); \
    const int rn = rowbase + tn; \
    rk_pf = rkb[rn*DD + h*HDIM + l]; \
    v_pf  = vals[((size_t)rn*MM + ROT)*DD + h*HDIM + kk]; \
    const float* pn = proj + (size_t)rn*28; \
    g_pf = pn[h]; bt_pf = pn[4+ROT*4+h]; al_pf = pn[12+ROT*4+h]; \
    l0_pf = pn[20+h*2]; l1_pf = pn[20+h*2+1]; } \
  float sp = alr + db; sp = (sp > 15.f) ? sp : log1pf(__expf(sp)); \
  const float dc = __expf(-Al*sp); \
  const float bt = 1.f/(1.f+__expf(-btl)); \
  const float mx = fmaxf(q0, q1); \
  const float e0 = __expf(q0-mx), e1 = __expf(q1-mx); \
  const float bl = (ROT ? e1 : e0)/(e0+e1); \
  const float gs = 1.f/(1.f+__expf(-gv)); \
  float pp0=0.f, pp1=0.f, pp2=0.f, pp3=0.f; \
  _Pragma("unroll") \
  for (int j = 0; j < 8; ++j){ float4 r = RPRV[j]; \
    if (ROT == 0){ \
      pp0 = fmaf(S[4*j+0], r.x, pp0); pp1 = fmaf(S[4*j+1], r.y, pp1); \
      pp2 = fmaf(S[4*j+2], r.z, pp2); pp3 = fmaf(S[4*j+3], r.w, pp3); \
    } else { \
      pp0 = fmaf(S[4*j+0], -r.y, pp0); pp1 = fmaf(S[4*j+1], r.x, pp1); \
      pp2 = fmaf(S[4*j+2], -r.w, pp2); pp3 = fmaf(S[4*j+3], r.z, pp3); } } \
  float pp = (pp0+pp1)+(pp2+pp3); \
  pp += __shfl_xor(pp, 1, 64); \
  const float err = (v - dc*pp)*bt; \
  _Pragma("unroll") \
  for (int j = 0; j < 8; ++j) RCUR[j] = *(const float4*)&rs_my[PH][dbase + 4*j]; \
  float rr0=0.f, rr1=0.f, rr2=0.f, rr3=0.f; \
  _Pragma("unroll") \
  for (int j = 0; j < 8; ++j){ float4 rp = RPRV[j]; float4 rc = RCUR[j]; \
    float w0,w1,w2,w3,c0,c1,c2,c3; \
    if (ROT == 0){ w0=rp.x; w1=rp.y; w2=rp.z; w3=rp.w; c0=rc.x; c1=rc.y; c2=rc.z; c3=rc.w; } \
    else { w0=-rp.y; w1=rp.x; w2=-rp.w; w3=rp.z; c0=-rc.y; c1=rc.x; c2=-rc.w; c3=rc.z; } \
    S[4*j+0] = fmaf(S[4*j+0], dc, w0*err); rr0 = fmaf(S[4*j+0], c0, rr0); \
    S[4*j+1] = fmaf(S[4*j+1], dc, w1*err); rr1 = fmaf(S[4*j+1], c1, rr1); \
    S[4*j+2] = fmaf(S[4*j+2], dc, w2*err); rr2 = fmaf(S[4*j+2], c2, rr2); \
    S[4*j+3] = fmaf(S[4*j+3], dc, w3*err); rr3 = fmaf(S[4*j+3], c3, rr3); } \
  float rr = (rr0+rr1)+(rr2+rr3); \
  rr += __shfl_xor(rr, 1, 64); \
  if (half == 0) part[row*DD + h*HDIM + kk] = gs*bl*rr; \
}

template<int ROT>
__device__ __forceinline__ void scan_body(int b, int h, int l, int kk, int half, int dbase,
    const float* __restrict__ vals, const float* __restrict__ rkb,
    const float* __restrict__ proj, float Al, float db,
    float* __restrict__ part, float (*rs_my)[64])
{
  const int rowbase = b*TT;
  float S[32];
  #pragma unroll
  for (int j = 0; j < 32; ++j) S[j] = 0.f;
  float4 rkA[8], rkB[8];
  #pragma unroll
  for (int j = 0; j < 8; ++j){ rkB[j].x = 0.f; rkB[j].y = 0.f; rkB[j].z = 0.f; rkB[j].w = 0.f; }
  // prefetch t = 0
  float rk_pf = rkb[rowbase*DD + h*HDIM + l];
  float v_pf  = vals[((size_t)rowbase*MM + ROT)*DD + h*HDIM + kk];
  const float* pc = proj + (size_t)rowbase*28;
  float g_pf = pc[h], bt_pf = pc[4+ROT*4+h], al_pf = pc[12+ROT*4+h];
  float l0_pf = pc[20+h*2], l1_pf = pc[20+h*2+1];
  for (int t = 0; t < TT; t += 2){
    STEP(t,   0, rkA, rkB)
    STEP(t+1, 1, rkB, rkA)
  }
}

__global__ void __launch_bounds__(128) k_scan(const float* __restrict__ vals,
                                              const float* __restrict__ rkb,
                                              const float* __restrict__ proj,
                                              const float* __restrict__ A_log,
                                              const float* __restrict__ dt_bias,
                                              float* __restrict__ partials){
  const int bi = blockIdx.x;      // ((b*HH)+h)*MM + m
  const int m  = bi & 1;
  const int h  = (bi >> 1) & 3;
  const int b  = bi >> 3;
  const int tid = threadIdx.x;
  const int w = tid >> 6, l = tid & 63;
  const int half = l & 1, kk = w*32 + (l >> 1), dbase = half*32;
  __shared__ float rs[2][2][64];   // [wave][slot][elem] — per-wave private copy
  float (*rs_my)[64] = rs[w];
  float* part = partials + (size_t)m*(BB*TT*DD);
  const float Al = __expf(A_log[m*HH + h]);
  const float db = dt_bias[m*HH + h];
  if (m == 0) scan_body<0>(b, h, l, kk, half, dbase, vals, rkb, proj, Al, db, part, rs_my);
  else        scan_body<1>(b, h, l, kk, half, dbase, vals, rkb, proj, Al, db, part, rs_my);
}

// ---------------- combine partial outputs: o = p0 + p1 ----------------
__global__ void k_comb(const float* __restrict__ a, const float* __restrict__ b,
                       float* __restrict__ o){
  int i = blockIdx.x*256 + threadIdx.x;
  float4 x = ((const float4*)a)[i];
  float4 y = ((const float4*)b)[i];
  x.x += y.x; x.y += y.y; x.z += y.z; x.w += y.w;
  ((float4*)o)[i] = x;
}

// ---------------- residual: x += y + z ----------------
__global__ void k_resid(float* __restrict__ x, const float* __restrict__ y,
                        const float* __restrict__ z){
  int i = blockIdx.x*256 + threadIdx.x;
  float4* x4 = (float4*)x;
  const float4* y4 = (const float4*)y;
  const float4* z4 = (const float4*)z;
  float4 a = x4[i], bq = y4[i], c = z4[i];
  a.x += bq.x + c.x; a.y += bq.y + c.y; a.z += bq.z + c.z; a.w += bq.w + c.w;
  x4[i] = a;
}

extern "C" void kernel_launch(void* const* d_in, const int* in_sizes, int n_in,
                              void* d_out, int out_size, void* d_ws, size_t ws_size,
                              hipStream_t stream){
  const int*   ids   = (const int*)d_in[0];
  const float* emb   = (const float*)d_in[1];
  const float* normw = (const float*)d_in[2];
  const float* Wup   = (const float*)d_in[3];
  const float* Wgate = (const float*)d_in[4];
  const float* Wdown = (const float*)d_in[5];
  const float* convw = (const float*)d_in[6];
  const float* convb = (const float*)d_in[7];
  const float* Wv    = (const float*)d_in[8];
  const float* Wg    = (const float*)d_in[9];
  const float* Wb    = (const float*)d_in[10];
  const float* Wa    = (const float*)d_in[11];
  const float* A_log = (const float*)d_in[12];
  const float* dtb   = (const float*)d_in[13];
  const float* Wbl   = (const float*)d_in[14];
  const float* Wout  = (const float*)d_in[15];
  const float* fnw   = (const float*)d_in[16];
  float* out = (float*)d_out;

  const int ROWS = BB*TT;              // 4096
  const size_t MEG = 1u << 20;         // 1,048,576 floats
  float* ws   = (float*)d_ws;
  float* x    = ws;                    // 1M
  float* nx   = x    + MEG;            // 1M
  float* big1 = nx   + MEG;            // 2M : u, then vals, then obuf
  float* big2 = big1 + 2*MEG;          // 2M : g/hh, then partials, then z
  float* y    = big2 + 2*MEG;          // 1M
  float* proj = y    + MEG;            // 4096*28
  float* rkb  = proj + (1u<<17);       // 1M
  float* Wp   = rkb  + MEG;            // 256*28

  k_embed<<<ROWS, DD, 0, stream>>>(ids, emb, x);

  for (int l = 0; l < LL; ++l){
    k_rmsnorm<<<ROWS, 64, 0, stream>>>(x, normw + l*DD, nx);
    float* u = big1; float* g = big2;
    k_gemm<false><<<dim3(DIM/64, ROWS/64), 256, 0, stream>>>(nx, Wup + (size_t)l*DD*DIM, u, DIM, DD);
    k_gemm<false><<<dim3(DIM/64, ROWS/64), 256, 0, stream>>>(nx, Wgate + (size_t)l*DD*DIM, g, DIM, DD);
    k_conv<<<(ROWS*DIM)/256, 256, 0, stream>>>(u, g, convw + l*DIM*KW, convb + l*DIM, g);
    k_gemm<false><<<dim3(DD/64, ROWS/64), 256, 0, stream>>>(g, Wdown + (size_t)l*DIM*DD, y, DD, DIM);
    float* vals = big1;
    k_gemm<false><<<dim3((MM*DD)/64, ROWS/64), 256, 0, stream>>>(y, Wv + (size_t)l*DD*MM*DD, vals, MM*DD, DD);
    k_pack<<<DD, 32, 0, stream>>>(Wg + l*DD*HH, Wb + l*MM*DD*HH, Wa + l*MM*DD*HH,
                                  Wbl + l*DD*HH*MM, Wp);
    k_gemm<false><<<dim3(1, ROWS/64), 256, 0, stream>>>(y, Wp, proj, 28, DD);
    k_rk<<<ROWS*HH, 64, 0, stream>>>(y, rkb);
    // scan: partials in big2 (2 x 1M), vals still in big1
    k_scan<<<BB*HH*MM, 128, 0, stream>>>(vals, rkb, proj, A_log + l*MM*HH, dtb + l*MM*HH, big2);
    // combine into big1 (vals dead now)
    float* obuf = big1;
    k_comb<<<(ROWS*DD/4)/256, 256, 0, stream>>>(big2, big2 + MEG, obuf);
    float* z = big2;   // overwrite partial0
    k_gemm<false><<<dim3(DD/64, ROWS/64), 256, 0, stream>>>(obuf, Wout + (size_t)l*DD*DD, z, DD, DD);
    k_resid<<<(ROWS*DD)/1024, 256, 0, stream>>>(x, y, z);
  }

  k_rmsnorm<<<ROWS, 64, 0, stream>>>(x, fnw, nx);
  k_gemm<true><<<dim3((VV+63)/64, ROWS/64), 256, 0, stream>>>(nx, emb, out, VV, DD);
}

// Round 3
// 1139.966 us; speedup vs baseline: 3.2356x; 1.4767x over previous
//
#include <hip/hip_runtime.h>
#include <math.h>

#define BB 8
#define TT 512
#define DD 256
#define DIM 512
#define KW 4
#define MM 2
#define HH 4
#define HDIM 64
#define LL 2
#define VV 272

__device__ __forceinline__ float sigf(float x){ return 1.f/(1.f+__expf(-x)); }
__device__ __forceinline__ float siluf(float x){ return x/(1.f+__expf(-x)); }

// async global->LDS, 16B per lane. LDS dest must be wave-uniform base;
// HW writes base + lane*16. Global src is per-lane.
__device__ __forceinline__ void gl_lds16(const float* g, float* l){
  __builtin_amdgcn_global_load_lds(
      (const __attribute__((address_space(1))) unsigned int*)g,
      (__attribute__((address_space(3))) unsigned int*)l,
      16, 0, 0);
}

// ---------------- embedding gather ----------------
__global__ void k_embed(const int* __restrict__ ids, const float* __restrict__ emb,
                        float* __restrict__ x){
  int row = blockIdx.x;            // b*T+t
  int d = threadIdx.x;             // 256
  x[row*DD + d] = emb[ids[row]*DD + d];
}

// ---------------- rmsnorm (row of 256), 1 wave/row ----------------
__global__ void k_rmsnorm(const float* __restrict__ in, const float* __restrict__ w,
                          float* __restrict__ out){
  int row = blockIdx.x;
  int l = threadIdx.x;             // 64
  float4 v = *(const float4*)&in[row*DD + l*4];
  float ss = v.x*v.x + v.y*v.y + v.z*v.z + v.w*v.w;
  #pragma unroll
  for (int o = 32; o > 0; o >>= 1) ss += __shfl_xor(ss, o, 64);
  float sc = rsqrtf(ss*(1.f/DD) + 1e-6f);
  float4 wv = *(const float4*)&w[l*4];
  float4 r;
  r.x = v.x*sc*wv.x; r.y = v.y*sc*wv.y; r.z = v.z*sc*wv.z; r.w = v.w*sc*wv.w;
  *(float4*)&out[row*DD + l*4] = r;
}

// ---------------- generic f32 GEMM: C[4096,N] = A[4096,K] @ B ----------------
template<bool BT>
__global__ void __launch_bounds__(256) k_gemm(const float* __restrict__ A,
                                              const float* __restrict__ B,
                                              float* __restrict__ C, int N, int K){
  __shared__ float as[16][65];
  __shared__ float bs[16][65];
  int tid = threadIdx.x;
  int tx = tid & 15, ty = tid >> 4;
  int m0 = blockIdx.y * 64, n0 = blockIdx.x * 64;
  float acc[4][4] = {};
  for (int k0 = 0; k0 < K; k0 += 16){
    #pragma unroll
    for (int i = tid; i < 1024; i += 256){
      int mm = i >> 4, kk = i & 15;
      as[kk][mm] = A[(m0+mm)*K + k0 + kk];
    }
    if (!BT){
      #pragma unroll
      for (int i = tid; i < 1024; i += 256){
        int kk = i >> 6, nn = i & 63;
        int n = n0 + nn;
        bs[kk][nn] = (n < N) ? B[(size_t)(k0+kk)*N + n] : 0.f;
      }
    } else {
      #pragma unroll
      for (int i = tid; i < 1024; i += 256){
        int nn = i >> 4, kk = i & 15;
        int n = n0 + nn;
        bs[kk][nn] = (n < N) ? B[(size_t)n*K + k0 + kk] : 0.f;
      }
    }
    __syncthreads();
    #pragma unroll
    for (int kk = 0; kk < 16; ++kk){
      float a[4], bv[4];
      #pragma unroll
      for (int j = 0; j < 4; ++j){ a[j] = as[kk][ty*4+j]; bv[j] = bs[kk][tx*4+j]; }
      #pragma unroll
      for (int i = 0; i < 4; ++i)
        #pragma unroll
        for (int j = 0; j < 4; ++j) acc[i][j] = fmaf(a[i], bv[j], acc[i][j]);
    }
    __syncthreads();
  }
  int n = n0 + tx*4;
  if (n < N){
    #pragma unroll
    for (int i = 0; i < 4; ++i){
      float4 r; r.x = acc[i][0]; r.y = acc[i][1]; r.z = acc[i][2]; r.w = acc[i][3];
      *(float4*)&C[(size_t)(m0+ty*4+i)*N + n] = r;
    }
  }
}

// ---------------- causal depthwise conv + silu gating --------
__global__ void k_conv(const float* __restrict__ u, const float* __restrict__ g,
                       const float* __restrict__ cw, const float* __restrict__ cb,
                       float* __restrict__ hh){
  int idx = blockIdx.x*256 + threadIdx.x;  // over B*T*DIM
  int c  = idx % DIM;
  int bt = idx / DIM;
  int t  = bt % TT;
  float acc = cb[c];
  #pragma unroll
  for (int j = 0; j < KW; ++j){
    int dt_ = j - (KW-1);
    if (t + dt_ >= 0) acc = fmaf(u[(bt + dt_)*DIM + c], cw[c*KW + j], acc);
  }
  float h = siluf(acc);
  hh[idx] = siluf(g[idx]) * h;
}

// ---------------- pack small projection weights into (D, 28) ----------------
// cols: 0..3 gate(h) | 4..11 beta(m,h) | 12..19 alpha(m,h) | 20..27 blend(h*2+m)
__global__ void k_pack(const float* __restrict__ Wg, const float* __restrict__ Wb,
                       const float* __restrict__ Wa, const float* __restrict__ Wbl,
                       float* __restrict__ Wp){
  int d = blockIdx.x;     // 256
  int j = threadIdx.x;    // 32 (28 used)
  if (j >= 28) return;
  float v;
  if (j < 4)        v = Wg[d*HH + j];
  else if (j < 12){ int m=(j-4)>>2, h=(j-4)&3;  v = Wb[(m*DD + d)*HH + h]; }
  else if (j < 20){ int m=(j-12)>>2, h=(j-12)&3; v = Wa[(m*DD + d)*HH + h]; }
  else              v = Wbl[d*(HH*MM) + (j-20)];
  Wp[d*28 + j] = v;
}

// ---------------- rk normalization: unit-norm per (b,t,h) over 64 ----------
__global__ void k_rk(const float* __restrict__ y, float* __restrict__ rkb){
  int blk = blockIdx.x;          // B*T*H
  int lane = threadIdx.x;        // 64
  int row = blk >> 2, h = blk & 3;
  float v = y[row*DD + h*HDIM + lane];
  float ss = v*v;
  #pragma unroll
  for (int o = 32; o > 0; o >>= 1) ss += __shfl_xor(ss, o, 64);
  float nrm = fmaxf(sqrtf(ss), 1e-12f);
  rkb[row*DD + h*HDIM + lane] = v / nrm;
}

// ---------------- precompute scan scalars: dc, beta, blend*gate ----------
// scal layout: [row][m][h][4] = {dc, bt, bl*gs, 0}; row stride 32 floats.
__global__ void k_scal(const float* __restrict__ proj, const float* __restrict__ A_log,
                       const float* __restrict__ dtb, float* __restrict__ scal){
  int i = blockIdx.x*256 + threadIdx.x;   // over ROWS*MM*HH = 32768
  int mh = i & 7;
  int row = i >> 3;
  int m = mh >> 2, h = mh & 3;
  const float* pv = proj + (size_t)row*28;
  float gs  = sigf(pv[h]);
  float btv = sigf(pv[4 + m*4 + h]);
  float sp  = pv[12 + m*4 + h] + dtb[m*HH + h];
  sp = (sp > 15.f) ? sp : log1pf(__expf(sp));
  float dc  = __expf(-__expf(A_log[m*HH + h]) * sp);
  float l0 = pv[20 + h*2], l1 = pv[20 + h*2 + 1];
  float mx = fmaxf(l0, l1);
  float e0 = __expf(l0-mx), e1 = __expf(l1-mx);
  float bl = (m ? e1 : e0) / (e0 + e1);
  float4 o; o.x = dc; o.y = btv; o.z = bl*gs; o.w = 0.f;
  *(float4*)&scal[((size_t)row*MM + m)*(HH*4) + h*4] = o;
}

// ---------------- sequential delta-memory scan, LDS chunk-staged ----------
// grid: B*H*M blocks of 128 threads (2 waves). wave w: k in [w*32,w*32+32);
// lane = 2*kk_local + half; half owns d in [half*32, half*32+32).
// Per chunk of 64 timesteps: stage rk/v/scal into LDS (global_load_lds x16B,
// double-buffered, issued right after the chunk barrier so HBM latency hides
// under the previous chunk's compute). wk(t)=rk(t-1) carried in registers.

#define SSTEP(TT_, RCUR, RPRV) { \
  const int row = rowchunk + (TT_); \
  const float4 sc4 = *(const float4*)&s_sc[p][TT_][0]; \
  const float dc = sc4.x, btv = sc4.y, blg = sc4.z; \
  const float v = s_v[p][TT_][kk]; \
  float pp0=0.f, pp1=0.f, pp2=0.f, pp3=0.f; \
  _Pragma("unroll") \
  for (int j = 0; j < 8; ++j){ const float4 r = RPRV[j]; \
    if (ROT == 0){ \
      pp0 = fmaf(S[4*j+0], r.x, pp0); pp1 = fmaf(S[4*j+1], r.y, pp1); \
      pp2 = fmaf(S[4*j+2], r.z, pp2); pp3 = fmaf(S[4*j+3], r.w, pp3); \
    } else { \
      pp0 = fmaf(S[4*j+0], -r.y, pp0); pp1 = fmaf(S[4*j+1], r.x, pp1); \
      pp2 = fmaf(S[4*j+2], -r.w, pp2); pp3 = fmaf(S[4*j+3], r.z, pp3); } } \
  float pp = (pp0+pp1)+(pp2+pp3); \
  pp += __shfl_xor(pp, 1, 64); \
  const float err = (v - dc*pp)*btv; \
  _Pragma("unroll") \
  for (int j = 0; j < 8; ++j) RCUR[j] = *(const float4*)&s_rk[p][TT_][dbase + 4*j]; \
  float rr0=0.f, rr1=0.f, rr2=0.f, rr3=0.f; \
  _Pragma("unroll") \
  for (int j = 0; j < 8; ++j){ const float4 rp = RPRV[j]; const float4 rc = RCUR[j]; \
    float w0,w1,w2,w3,c0,c1,c2,c3; \
    if (ROT == 0){ w0=rp.x; w1=rp.y; w2=rp.z; w3=rp.w; c0=rc.x; c1=rc.y; c2=rc.z; c3=rc.w; } \
    else { w0=-rp.y; w1=rp.x; w2=-rp.w; w3=rp.z; c0=-rc.y; c1=rc.x; c2=-rc.w; c3=rc.z; } \
    S[4*j+0] = fmaf(S[4*j+0], dc, w0*err); rr0 = fmaf(S[4*j+0], c0, rr0); \
    S[4*j+1] = fmaf(S[4*j+1], dc, w1*err); rr1 = fmaf(S[4*j+1], c1, rr1); \
    S[4*j+2] = fmaf(S[4*j+2], dc, w2*err); rr2 = fmaf(S[4*j+2], c2, rr2); \
    S[4*j+3] = fmaf(S[4*j+3], dc, w3*err); rr3 = fmaf(S[4*j+3], c3, rr3); } \
  float rr = (rr0+rr1)+(rr2+rr3); \
  rr += __shfl_xor(rr, 1, 64); \
  if (half == 0) part[(size_t)row*DD + h*HDIM + kk] = blg*rr; \
}

template<int ROT>
__device__ __forceinline__ void scan_body(int b, int h, int tid,
    const float* __restrict__ vals, const float* __restrict__ rkb,
    const float* __restrict__ scal, float* __restrict__ part,
    float (*s_rk)[64][64], float (*s_v)[64][64], float (*s_sc)[64][4])
{
  const int wid = tid >> 6, l = tid & 63;
  const int half = l & 1, kk = wid*32 + (l >> 1), dbase = half*32;
  const int rowbase = b*TT;

  float S[32];
  #pragma unroll
  for (int j = 0; j < 32; ++j) S[j] = 0.f;
  float4 rkA[8], rkB[8];
  #pragma unroll
  for (int j = 0; j < 8; ++j){ rkB[j].x=0.f; rkB[j].y=0.f; rkB[j].z=0.f; rkB[j].w=0.f; }

  auto stage = [&](int c, int pbuf){
    const int r0 = rowbase + c*64;
    if (wid == 0){
      #pragma unroll
      for (int i = 0; i < 16; ++i){
        const float* g = rkb + (size_t)(r0 + i*4 + (l>>4))*DD + h*HDIM + (l&15)*4;
        gl_lds16(g, &s_rk[pbuf][i*4][0]);
      }
      const float* gsc = scal + ((size_t)(r0 + l)*MM + ROT)*(HH*4) + h*4;
      gl_lds16(gsc, &s_sc[pbuf][0][0]);
    } else {
      #pragma unroll
      for (int i = 0; i < 16; ++i){
        const float* g = vals + ((size_t)(r0 + i*4 + (l>>4))*MM + ROT)*DD + h*HDIM + (l&15)*4;
        gl_lds16(g, &s_v[pbuf][i*4][0]);
      }
    }
  };

  stage(0, 0);
  for (int c = 0; c < TT/64; ++c){
    const int p = c & 1;
    __syncthreads();                 // drains own vmcnt -> chunk c staged by all
    if (c + 1 < TT/64) stage(c+1, p^1);
    const int rowchunk = rowbase + c*64;
    for (int tt = 0; tt < 64; tt += 2){
      SSTEP(tt,   rkA, rkB)
      SSTEP(tt+1, rkB, rkA)
    }
  }
}

__global__ void __launch_bounds__(128) k_scan(const float* __restrict__ vals,
                                              const float* __restrict__ rkb,
                                              const float* __restrict__ scal,
                                              float* __restrict__ partials){
  __shared__ float s_rk[2][64][64];
  __shared__ float s_v [2][64][64];
  __shared__ float s_sc[2][64][4];
  const int bi = blockIdx.x;      // ((b*HH)+h)*MM + m
  const int m  = bi & 1;
  const int h  = (bi >> 1) & 3;
  const int b  = bi >> 3;
  float* part = partials + (size_t)m*(BB*TT*DD);
  if (m == 0) scan_body<0>(b, h, threadIdx.x, vals, rkb, scal, part, s_rk, s_v, s_sc);
  else        scan_body<1>(b, h, threadIdx.x, vals, rkb, scal, part, s_rk, s_v, s_sc);
}

// ---------------- combine partial outputs: o = p0 + p1 ----------------
__global__ void k_comb(const float* __restrict__ a, const float* __restrict__ b,
                       float* __restrict__ o){
  int i = blockIdx.x*256 + threadIdx.x;
  float4 x = ((const float4*)a)[i];
  float4 y = ((const float4*)b)[i];
  x.x += y.x; x.y += y.y; x.z += y.z; x.w += y.w;
  ((float4*)o)[i] = x;
}

// ---------------- residual: x += y + z ----------------
__global__ void k_resid(float* __restrict__ x, const float* __restrict__ y,
                        const float* __restrict__ z){
  int i = blockIdx.x*256 + threadIdx.x;
  float4* x4 = (float4*)x;
  const float4* y4 = (const float4*)y;
  const float4* z4 = (const float4*)z;
  float4 a = x4[i], bq = y4[i], c = z4[i];
  a.x += bq.x + c.x; a.y += bq.y + c.y; a.z += bq.z + c.z; a.w += bq.w + c.w;
  x4[i] = a;
}

extern "C" void kernel_launch(void* const* d_in, const int* in_sizes, int n_in,
                              void* d_out, int out_size, void* d_ws, size_t ws_size,
                              hipStream_t stream){
  const int*   ids   = (const int*)d_in[0];
  const float* emb   = (const float*)d_in[1];
  const float* normw = (const float*)d_in[2];
  const float* Wup   = (const float*)d_in[3];
  const float* Wgate = (const float*)d_in[4];
  const float* Wdown = (const float*)d_in[5];
  const float* convw = (const float*)d_in[6];
  const float* convb = (const float*)d_in[7];
  const float* Wv    = (const float*)d_in[8];
  const float* Wg    = (const float*)d_in[9];
  const float* Wb    = (const float*)d_in[10];
  const float* Wa    = (const float*)d_in[11];
  const float* A_log = (const float*)d_in[12];
  const float* dtb   = (const float*)d_in[13];
  const float* Wbl   = (const float*)d_in[14];
  const float* Wout  = (const float*)d_in[15];
  const float* fnw   = (const float*)d_in[16];
  float* out = (float*)d_out;

  const int ROWS = BB*TT;              // 4096
  const size_t MEG = 1u << 20;         // 1,048,576 floats
  float* ws   = (float*)d_ws;
  float* x    = ws;                    // 1M
  float* nx   = x    + MEG;            // 1M
  float* big1 = nx   + MEG;            // 2M : u, then vals, then obuf
  float* big2 = big1 + 2*MEG;          // 2M : g/hh, then partials, then z
  float* y    = big2 + 2*MEG;          // 1M
  float* proj = y    + MEG;            // 128K
  float* rkb  = proj + (1u<<17);       // 1M
  float* Wp   = rkb  + MEG;            // 8K
  float* scal = Wp   + 8192;           // 128K

  k_embed<<<ROWS, DD, 0, stream>>>(ids, emb, x);

  for (int l = 0; l < LL; ++l){
    k_rmsnorm<<<ROWS, 64, 0, stream>>>(x, normw + l*DD, nx);
    float* u = big1; float* g = big2;
    k_gemm<false><<<dim3(DIM/64, ROWS/64), 256, 0, stream>>>(nx, Wup + (size_t)l*DD*DIM, u, DIM, DD);
    k_gemm<false><<<dim3(DIM/64, ROWS/64), 256, 0, stream>>>(nx, Wgate + (size_t)l*DD*DIM, g, DIM, DD);
    k_conv<<<(ROWS*DIM)/256, 256, 0, stream>>>(u, g, convw + l*DIM*KW, convb + l*DIM, g);
    k_gemm<false><<<dim3(DD/64, ROWS/64), 256, 0, stream>>>(g, Wdown + (size_t)l*DIM*DD, y, DD, DIM);
    float* vals = big1;
    k_gemm<false><<<dim3((MM*DD)/64, ROWS/64), 256, 0, stream>>>(y, Wv + (size_t)l*DD*MM*DD, vals, MM*DD, DD);
    k_pack<<<DD, 32, 0, stream>>>(Wg + l*DD*HH, Wb + l*MM*DD*HH, Wa + l*MM*DD*HH,
                                  Wbl + l*DD*HH*MM, Wp);
    k_gemm<false><<<dim3(1, ROWS/64), 256, 0, stream>>>(y, Wp, proj, 28, DD);
    k_scal<<<(ROWS*MM*HH)/256, 256, 0, stream>>>(proj, A_log + l*MM*HH, dtb + l*MM*HH, scal);
    k_rk<<<ROWS*HH, 64, 0, stream>>>(y, rkb);
    // scan: partials in big2 (2 x 1M), vals still in big1
    k_scan<<<BB*HH*MM, 128, 0, stream>>>(vals, rkb, scal, big2);
    // combine into big1 (vals dead now)
    float* obuf = big1;
    k_comb<<<(ROWS*DD/4)/256, 256, 0, stream>>>(big2, big2 + MEG, obuf);
    float* z = big2;   // overwrite partial0
    k_gemm<false><<<dim3(DD/64, ROWS/64), 256, 0, stream>>>(obuf, Wout + (size_t)l*DD*DD, z, DD, DD);
    k_resid<<<(ROWS*DD)/1024, 256, 0, stream>>>(x, y, z);
  }

  k_rmsnorm<<<ROWS, 64, 0, stream>>>(x, fnw, nx);
  k_gemm<true><<<dim3((VV+63)/64, ROWS/64), 256, 0, stream>>>(nx, emb, out, VV, DD);
}

// Round 4
// 933.241 us; speedup vs baseline: 3.9523x; 1.2215x over previous
//
#include <hip/hip_runtime.h>
#include <math.h>

#define BB 8
#define TT 512
#define DD 256
#define DIM 512
#define KW 4
#define MM 2
#define HH 4
#define HDIM 64
#define LL 2
#define VV 272

__device__ __forceinline__ float sigf(float x){ return 1.f/(1.f+__expf(-x)); }
__device__ __forceinline__ float siluf(float x){ return x/(1.f+__expf(-x)); }

// lane <-> lane^1 reduce via DPP quad_perm [1,0,3,2] — pure VALU, no DS op.
__device__ __forceinline__ float xor1_add(float x){
  int y = __builtin_amdgcn_update_dpp(0, __float_as_int(x), 0xB1, 0xF, 0xF, true);
  return x + __int_as_float(y);
}

// async global->LDS, 16B per lane. LDS dest must be wave-uniform base;
// HW writes base + lane*16. Global src is per-lane.
__device__ __forceinline__ void gl_lds16(const float* g, float* l){
  __builtin_amdgcn_global_load_lds(
      (const __attribute__((address_space(1))) unsigned int*)g,
      (__attribute__((address_space(3))) unsigned int*)l,
      16, 0, 0);
}

// ---------------- embedding gather ----------------
__global__ void k_embed(const int* __restrict__ ids, const float* __restrict__ emb,
                        float* __restrict__ x){
  int row = blockIdx.x;            // b*T+t
  int d = threadIdx.x;             // 256
  x[row*DD + d] = emb[ids[row]*DD + d];
}

// ---------------- rmsnorm (row of 256), 1 wave/row ----------------
__global__ void k_rmsnorm(const float* __restrict__ in, const float* __restrict__ w,
                          float* __restrict__ out){
  int row = blockIdx.x;
  int l = threadIdx.x;             // 64
  float4 v = *(const float4*)&in[row*DD + l*4];
  float ss = v.x*v.x + v.y*v.y + v.z*v.z + v.w*v.w;
  #pragma unroll
  for (int o = 32; o > 0; o >>= 1) ss += __shfl_xor(ss, o, 64);
  float sc = rsqrtf(ss*(1.f/DD) + 1e-6f);
  float4 wv = *(const float4*)&w[l*4];
  float4 r;
  r.x = v.x*sc*wv.x; r.y = v.y*sc*wv.y; r.z = v.z*sc*wv.z; r.w = v.w*sc*wv.w;
  *(float4*)&out[row*DD + l*4] = r;
}

// ---------------- f32 GEMM: C[4096,N] = A[4096,K] @ B ----------------
// 64x64 tile, 128 threads (2 waves), 8 rows x 4 cols per thread.
// BT=false: B is (K,N) row-major.  BT=true: B is (N,K) row-major (C = A @ B^T).
template<bool BT>
__global__ void __launch_bounds__(128) k_gemm(const float* __restrict__ A,
                                              const float* __restrict__ B,
                                              float* __restrict__ C, int N, int K){
  __shared__ float as[16][68];
  __shared__ float bs[16][68];
  const int tid = threadIdx.x;
  const int tx = tid & 15, ty = tid >> 4;
  const int m0 = blockIdx.y * 64, n0 = blockIdx.x * 64;
  float acc[8][4] = {};
  for (int k0 = 0; k0 < K; k0 += 16){
    // stage A (64 rows x 16 k): 2 float4 per thread, scatter-transpose to as[kk][mm]
    #pragma unroll
    for (int r = 0; r < 2; ++r){
      int idx = tid + r*128;
      int mm = idx >> 2, kk4 = (idx & 3) * 4;
      float4 a = *(const float4*)&A[(size_t)(m0+mm)*K + k0 + kk4];
      as[kk4+0][mm] = a.x; as[kk4+1][mm] = a.y; as[kk4+2][mm] = a.z; as[kk4+3][mm] = a.w;
    }
    // stage B (16 k x 64 cols)
    if (!BT){
      #pragma unroll
      for (int r = 0; r < 2; ++r){
        int idx = tid + r*128;
        int kk = idx >> 4, nn4 = (idx & 15) * 4;
        int n = n0 + nn4;
        float4 b = make_float4(0.f,0.f,0.f,0.f);
        if (n < N) b = *(const float4*)&B[(size_t)(k0+kk)*N + n];
        *(float4*)&bs[kk][nn4] = b;
      }
    } else {
      int nn = tid >> 1, kk8 = (tid & 1) * 8;
      int n = n0 + nn;
      float4 b0 = make_float4(0.f,0.f,0.f,0.f), b1 = b0;
      if (n < N){
        b0 = *(const float4*)&B[(size_t)n*K + k0 + kk8];
        b1 = *(const float4*)&B[(size_t)n*K + k0 + kk8 + 4];
      }
      bs[kk8+0][nn]=b0.x; bs[kk8+1][nn]=b0.y; bs[kk8+2][nn]=b0.z; bs[kk8+3][nn]=b0.w;
      bs[kk8+4][nn]=b1.x; bs[kk8+5][nn]=b1.y; bs[kk8+6][nn]=b1.z; bs[kk8+7][nn]=b1.w;
    }
    __syncthreads();
    #pragma unroll
    for (int kk = 0; kk < 16; ++kk){
      float ar[8], br[4];
      *(float4*)&ar[0] = *(const float4*)&as[kk][ty*4];
      *(float4*)&ar[4] = *(const float4*)&as[kk][32+ty*4];
      *(float4*)&br[0] = *(const float4*)&bs[kk][tx*4];
      #pragma unroll
      for (int i = 0; i < 8; ++i)
        #pragma unroll
        for (int j = 0; j < 4; ++j) acc[i][j] = fmaf(ar[i], br[j], acc[i][j]);
    }
    __syncthreads();
  }
  int n = n0 + tx*4;
  if (n < N){
    #pragma unroll
    for (int i = 0; i < 8; ++i){
      int row = m0 + ((i < 4) ? (ty*4 + i) : (32 + ty*4 + i - 4));
      float4 r; r.x=acc[i][0]; r.y=acc[i][1]; r.z=acc[i][2]; r.w=acc[i][3];
      *(float4*)&C[(size_t)row*N + n] = r;
    }
  }
}

// ---------------- causal depthwise conv + silu gating --------
__global__ void k_conv(const float* __restrict__ u, const float* __restrict__ g,
                       const float* __restrict__ cw, const float* __restrict__ cb,
                       float* __restrict__ hh){
  int idx = blockIdx.x*256 + threadIdx.x;  // over B*T*DIM
  int c  = idx % DIM;
  int bt = idx / DIM;
  int t  = bt % TT;
  float acc = cb[c];
  #pragma unroll
  for (int j = 0; j < KW; ++j){
    int dt_ = j - (KW-1);
    if (t + dt_ >= 0) acc = fmaf(u[(bt + dt_)*DIM + c], cw[c*KW + j], acc);
  }
  float h = siluf(acc);
  hh[idx] = siluf(g[idx]) * h;
}

// ---------------- pack small projection weights into (D, 28) ----------------
// cols: 0..3 gate(h) | 4..11 beta(m,h) | 12..19 alpha(m,h) | 20..27 blend(h*2+m)
__global__ void k_pack(const float* __restrict__ Wg, const float* __restrict__ Wb,
                       const float* __restrict__ Wa, const float* __restrict__ Wbl,
                       float* __restrict__ Wp){
  int d = blockIdx.x;     // 256
  int j = threadIdx.x;    // 32 (28 used)
  if (j >= 28) return;
  float v;
  if (j < 4)        v = Wg[d*HH + j];
  else if (j < 12){ int m=(j-4)>>2, h=(j-4)&3;  v = Wb[(m*DD + d)*HH + h]; }
  else if (j < 20){ int m=(j-12)>>2, h=(j-12)&3; v = Wa[(m*DD + d)*HH + h]; }
  else              v = Wbl[d*(HH*MM) + (j-20)];
  Wp[d*28 + j] = v;
}

// ---------------- rk normalization: unit-norm per (b,t,h) over 64 ----------
__global__ void k_rk(const float* __restrict__ y, float* __restrict__ rkb){
  int blk = blockIdx.x;          // B*T*H
  int lane = threadIdx.x;        // 64
  int row = blk >> 2, h = blk & 3;
  float v = y[row*DD + h*HDIM + lane];
  float ss = v*v;
  #pragma unroll
  for (int o = 32; o > 0; o >>= 1) ss += __shfl_xor(ss, o, 64);
  float nrm = fmaxf(sqrtf(ss), 1e-12f);
  rkb[row*DD + h*HDIM + lane] = v / nrm;
}

// ---------------- precompute scan scalars: dc, beta, blend*gate ----------
// scal layout: [row][m][h][4] = {dc, bt, bl*gs, 0}; row stride 32 floats.
__global__ void k_scal(const float* __restrict__ proj, const float* __restrict__ A_log,
                       const float* __restrict__ dtb, float* __restrict__ scal){
  int i = blockIdx.x*256 + threadIdx.x;   // over ROWS*MM*HH = 32768
  int mh = i & 7;
  int row = i >> 3;
  int m = mh >> 2, h = mh & 3;
  const float* pv = proj + (size_t)row*28;
  float gs  = sigf(pv[h]);
  float btv = sigf(pv[4 + m*4 + h]);
  float sp  = pv[12 + m*4 + h] + dtb[m*HH + h];
  sp = (sp > 15.f) ? sp : log1pf(__expf(sp));
  float dc  = __expf(-__expf(A_log[m*HH + h]) * sp);
  float l0 = pv[20 + h*2], l1 = pv[20 + h*2 + 1];
  float mx = fmaxf(l0, l1);
  float e0 = __expf(l0-mx), e1 = __expf(l1-mx);
  float bl = (m ? e1 : e0) / (e0 + e1);
  float4 o; o.x = dc; o.y = btv; o.z = bl*gs; o.w = 0.f;
  *(float4*)&scal[((size_t)row*MM + m)*(HH*4) + h*4] = o;
}

// ---------------- sequential delta-memory scan, LDS chunk-staged ----------
// grid: B*H*M blocks of 128 threads (2 waves). wave w: k in [w*32,w*32+32);
// lane = 2*kk_local + half; half owns d in [half*32, half*32+32).
// Cross-half reduces use DPP xor1_add (VALU) — no DS ops on the critical path.

#define SSTEP(TT_, RCUR, RPRV) { \
  const int row = rowchunk + (TT_); \
  const float4 sc4 = *(const float4*)&s_sc[p][TT_][0]; \
  const float dc = sc4.x, btv = sc4.y, blg = sc4.z; \
  const float v = s_v[p][TT_][kk]; \
  float pp0=0.f, pp1=0.f, pp2=0.f, pp3=0.f; \
  _Pragma("unroll") \
  for (int j = 0; j < 8; ++j){ const float4 r = RPRV[j]; \
    if (ROT == 0){ \
      pp0 = fmaf(S[4*j+0], r.x, pp0); pp1 = fmaf(S[4*j+1], r.y, pp1); \
      pp2 = fmaf(S[4*j+2], r.z, pp2); pp3 = fmaf(S[4*j+3], r.w, pp3); \
    } else { \
      pp0 = fmaf(S[4*j+0], -r.y, pp0); pp1 = fmaf(S[4*j+1], r.x, pp1); \
      pp2 = fmaf(S[4*j+2], -r.w, pp2); pp3 = fmaf(S[4*j+3], r.z, pp3); } } \
  float pp = (pp0+pp1)+(pp2+pp3); \
  pp = xor1_add(pp); \
  const float err = (v - dc*pp)*btv; \
  _Pragma("unroll") \
  for (int j = 0; j < 8; ++j) RCUR[j] = *(const float4*)&s_rk[p][TT_][dbase + 4*j]; \
  float rr0=0.f, rr1=0.f, rr2=0.f, rr3=0.f; \
  _Pragma("unroll") \
  for (int j = 0; j < 8; ++j){ const float4 rp = RPRV[j]; const float4 rc = RCUR[j]; \
    float w0,w1,w2,w3,c0,c1,c2,c3; \
    if (ROT == 0){ w0=rp.x; w1=rp.y; w2=rp.z; w3=rp.w; c0=rc.x; c1=rc.y; c2=rc.z; c3=rc.w; } \
    else { w0=-rp.y; w1=rp.x; w2=-rp.w; w3=rp.z; c0=-rc.y; c1=rc.x; c2=-rc.w; c3=rc.z; } \
    S[4*j+0] = fmaf(S[4*j+0], dc, w0*err); rr0 = fmaf(S[4*j+0], c0, rr0); \
    S[4*j+1] = fmaf(S[4*j+1], dc, w1*err); rr1 = fmaf(S[4*j+1], c1, rr1); \
    S[4*j+2] = fmaf(S[4*j+2], dc, w2*err); rr2 = fmaf(S[4*j+2], c2, rr2); \
    S[4*j+3] = fmaf(S[4*j+3], dc, w3*err); rr3 = fmaf(S[4*j+3], c3, rr3); } \
  float rr = (rr0+rr1)+(rr2+rr3); \
  rr = xor1_add(rr); \
  if (half == 0) part[(size_t)row*DD + h*HDIM + kk] = blg*rr; \
}

template<int ROT>
__device__ __forceinline__ void scan_body(int b, int h, int tid,
    const float* __restrict__ vals, const float* __restrict__ rkb,
    const float* __restrict__ scal, float* __restrict__ part,
    float (*s_rk)[64][64], float (*s_v)[64][64], float (*s_sc)[64][4])
{
  const int wid = tid >> 6, l = tid & 63;
  const int half = l & 1, kk = wid*32 + (l >> 1), dbase = half*32;
  const int rowbase = b*TT;

  float S[32];
  #pragma unroll
  for (int j = 0; j < 32; ++j) S[j] = 0.f;
  float4 rkA[8], rkB[8];
  #pragma unroll
  for (int j = 0; j < 8; ++j){ rkB[j].x=0.f; rkB[j].y=0.f; rkB[j].z=0.f; rkB[j].w=0.f; }

  auto stage = [&](int c, int pbuf){
    const int r0 = rowbase + c*64;
    if (wid == 0){
      #pragma unroll
      for (int i = 0; i < 16; ++i){
        const float* g = rkb + (size_t)(r0 + i*4 + (l>>4))*DD + h*HDIM + (l&15)*4;
        gl_lds16(g, &s_rk[pbuf][i*4][0]);
      }
      const float* gsc = scal + ((size_t)(r0 + l)*MM + ROT)*(HH*4) + h*4;
      gl_lds16(gsc, &s_sc[pbuf][0][0]);
    } else {
      #pragma unroll
      for (int i = 0; i < 16; ++i){
        const float* g = vals + ((size_t)(r0 + i*4 + (l>>4))*MM + ROT)*DD + h*HDIM + (l&15)*4;
        gl_lds16(g, &s_v[pbuf][i*4][0]);
      }
    }
  };

  stage(0, 0);
  for (int c = 0; c < TT/64; ++c){
    const int p = c & 1;
    __syncthreads();                 // drains own vmcnt -> chunk c staged by all
    if (c + 1 < TT/64) stage(c+1, p^1);
    const int rowchunk = rowbase + c*64;
    for (int tt = 0; tt < 64; tt += 2){
      SSTEP(tt,   rkA, rkB)
      SSTEP(tt+1, rkB, rkA)
    }
  }
}

__global__ void __launch_bounds__(128) k_scan(const float* __restrict__ vals,
                                              const float* __restrict__ rkb,
                                              const float* __restrict__ scal,
                                              float* __restrict__ partials){
  __shared__ float s_rk[2][64][64];
  __shared__ float s_v [2][64][64];
  __shared__ float s_sc[2][64][4];
  const int bi = blockIdx.x;      // ((b*HH)+h)*MM + m
  const int m  = bi & 1;
  const int h  = (bi >> 1) & 3;
  const int b  = bi >> 3;
  float* part = partials + (size_t)m*(BB*TT*DD);
  if (m == 0) scan_body<0>(b, h, threadIdx.x, vals, rkb, scal, part, s_rk, s_v, s_sc);
  else        scan_body<1>(b, h, threadIdx.x, vals, rkb, scal, part, s_rk, s_v, s_sc);
}

// ---------------- combine partial outputs: o = p0 + p1 ----------------
__global__ void k_comb(const float* __restrict__ a, const float* __restrict__ b,
                       float* __restrict__ o){
  int i = blockIdx.x*256 + threadIdx.x;
  float4 x = ((const float4*)a)[i];
  float4 y = ((const float4*)b)[i];
  x.x += y.x; x.y += y.y; x.z += y.z; x.w += y.w;
  ((float4*)o)[i] = x;
}

// ---------------- residual: x += y + z ----------------
__global__ void k_resid(float* __restrict__ x, const float* __restrict__ y,
                        const float* __restrict__ z){
  int i = blockIdx.x*256 + threadIdx.x;
  float4* x4 = (float4*)x;
  const float4* y4 = (const float4*)y;
  const float4* z4 = (const float4*)z;
  float4 a = x4[i], bq = y4[i], c = z4[i];
  a.x += bq.x + c.x; a.y += bq.y + c.y; a.z += bq.z + c.z; a.w += bq.w + c.w;
  x4[i] = a;
}

extern "C" void kernel_launch(void* const* d_in, const int* in_sizes, int n_in,
                              void* d_out, int out_size, void* d_ws, size_t ws_size,
                              hipStream_t stream){
  const int*   ids   = (const int*)d_in[0];
  const float* emb   = (const float*)d_in[1];
  const float* normw = (const float*)d_in[2];
  const float* Wup   = (const float*)d_in[3];
  const float* Wgate = (const float*)d_in[4];
  const float* Wdown = (const float*)d_in[5];
  const float* convw = (const float*)d_in[6];
  const float* convb = (const float*)d_in[7];
  const float* Wv    = (const float*)d_in[8];
  const float* Wg    = (const float*)d_in[9];
  const float* Wb    = (const float*)d_in[10];
  const float* Wa    = (const float*)d_in[11];
  const float* A_log = (const float*)d_in[12];
  const float* dtb   = (const float*)d_in[13];
  const float* Wbl   = (const float*)d_in[14];
  const float* Wout  = (const float*)d_in[15];
  const float* fnw   = (const float*)d_in[16];
  float* out = (float*)d_out;

  const int ROWS = BB*TT;              // 4096
  const size_t MEG = 1u << 20;         // 1,048,576 floats
  float* ws   = (float*)d_ws;
  float* x    = ws;                    // 1M
  float* nx   = x    + MEG;            // 1M
  float* big1 = nx   + MEG;            // 2M : u, then vals, then obuf
  float* big2 = big1 + 2*MEG;          // 2M : g/hh, then partials, then z
  float* y    = big2 + 2*MEG;          // 1M
  float* proj = y    + MEG;            // 128K
  float* rkb  = proj + (1u<<17);       // 1M
  float* Wp   = rkb  + MEG;            // 8K
  float* scal = Wp   + 8192;           // 128K

  k_embed<<<ROWS, DD, 0, stream>>>(ids, emb, x);

  for (int l = 0; l < LL; ++l){
    k_rmsnorm<<<ROWS, 64, 0, stream>>>(x, normw + l*DD, nx);
    float* u = big1; float* g = big2;
    k_gemm<false><<<dim3(DIM/64, ROWS/64), 128, 0, stream>>>(nx, Wup + (size_t)l*DD*DIM, u, DIM, DD);
    k_gemm<false><<<dim3(DIM/64, ROWS/64), 128, 0, stream>>>(nx, Wgate + (size_t)l*DD*DIM, g, DIM, DD);
    k_conv<<<(ROWS*DIM)/256, 256, 0, stream>>>(u, g, convw + l*DIM*KW, convb + l*DIM, g);
    k_gemm<false><<<dim3(DD/64, ROWS/64), 128, 0, stream>>>(g, Wdown + (size_t)l*DIM*DD, y, DD, DIM);
    float* vals = big1;
    k_gemm<false><<<dim3((MM*DD)/64, ROWS/64), 128, 0, stream>>>(y, Wv + (size_t)l*DD*MM*DD, vals, MM*DD, DD);
    k_pack<<<DD, 32, 0, stream>>>(Wg + l*DD*HH, Wb + l*MM*DD*HH, Wa + l*MM*DD*HH,
                                  Wbl + l*DD*HH*MM, Wp);
    k_gemm<false><<<dim3(1, ROWS/64), 128, 0, stream>>>(y, Wp, proj, 28, DD);
    k_scal<<<(ROWS*MM*HH)/256, 256, 0, stream>>>(proj, A_log + l*MM*HH, dtb + l*MM*HH, scal);
    k_rk<<<ROWS*HH, 64, 0, stream>>>(y, rkb);
    // scan: partials in big2 (2 x 1M), vals still in big1
    k_scan<<<BB*HH*MM, 128, 0, stream>>>(vals, rkb, scal, big2);
    // combine into big1 (vals dead now)
    float* obuf = big1;
    k_comb<<<(ROWS*DD/4)/256, 256, 0, stream>>>(big2, big2 + MEG, obuf);
    float* z = big2;   // overwrite partial0
    k_gemm<false><<<dim3(DD/64, ROWS/64), 128, 0, stream>>>(obuf, Wout + (size_t)l*DD*DD, z, DD, DD);
    k_resid<<<(ROWS*DD)/1024, 256, 0, stream>>>(x, y, z);
  }

  k_rmsnorm<<<ROWS, 64, 0, stream>>>(x, fnw, nx);
  k_gemm<true><<<dim3((VV+63)/64, ROWS/64), 128, 0, stream>>>(nx, emb, out, VV, DD);
}

// Round 5
// 768.355 us; speedup vs baseline: 4.8005x; 1.2146x over previous
//
#include <hip/hip_runtime.h>
#include <math.h>

#define BB 8
#define TT 512
#define DD 256
#define DIM 512
#define KW 4
#define MM 2
#define HH 4
#define HDIM 64
#define LL 2
#define VV 272

__device__ __forceinline__ float sigf(float x){ return 1.f/(1.f+__expf(-x)); }
__device__ __forceinline__ float siluf(float x){ return x/(1.f+__expf(-x)); }

// lane^1 and lane^2 reduces via DPP quad_perm — pure VALU, no DS ops.
__device__ __forceinline__ float xor1_add(float x){
  int y = __builtin_amdgcn_update_dpp(0, __float_as_int(x), 0xB1, 0xF, 0xF, true);
  return x + __int_as_float(y);
}
__device__ __forceinline__ float xor2_add(float x){
  int y = __builtin_amdgcn_update_dpp(0, __float_as_int(x), 0x4E, 0xF, 0xF, true);
  return x + __int_as_float(y);
}

// async global->LDS, 16B per lane. LDS dest must be wave-uniform base;
// HW writes base + lane*16. Global src is per-lane.
__device__ __forceinline__ void gl_lds16(const float* g, float* l){
  __builtin_amdgcn_global_load_lds(
      (const __attribute__((address_space(1))) unsigned int*)g,
      (__attribute__((address_space(3))) unsigned int*)l,
      16, 0, 0);
}

// ---------------- embedding gather ----------------
__global__ void k_embed(const int* __restrict__ ids, const float* __restrict__ emb,
                        float* __restrict__ x){
  int row = blockIdx.x;            // b*T+t
  int d = threadIdx.x;             // 256
  x[row*DD + d] = emb[ids[row]*DD + d];
}

// ---------------- rmsnorm (row of 256), 1 wave/row ----------------
__global__ void k_rmsnorm(const float* __restrict__ in, const float* __restrict__ w,
                          float* __restrict__ out){
  int row = blockIdx.x;
  int l = threadIdx.x;             // 64
  float4 v = *(const float4*)&in[row*DD + l*4];
  float ss = v.x*v.x + v.y*v.y + v.z*v.z + v.w*v.w;
  #pragma unroll
  for (int o = 32; o > 0; o >>= 1) ss += __shfl_xor(ss, o, 64);
  float sc = rsqrtf(ss*(1.f/DD) + 1e-6f);
  float4 wv = *(const float4*)&w[l*4];
  float4 r;
  r.x = v.x*sc*wv.x; r.y = v.y*sc*wv.y; r.z = v.z*sc*wv.z; r.w = v.w*sc*wv.w;
  *(float4*)&out[row*DD + l*4] = r;
}

// ---------------- f32 GEMM: C[4096,N] = A[4096,K] @ B ----------------
// 64x64 tile, 128 threads (2 waves), 8 rows x 4 cols per thread.
// BT=false: B is (K,N) row-major.  BT=true: B is (N,K) row-major (C = A @ B^T).
template<bool BT>
__global__ void __launch_bounds__(128) k_gemm(const float* __restrict__ A,
                                              const float* __restrict__ B,
                                              float* __restrict__ C, int N, int K){
  __shared__ float as[16][68];
  __shared__ float bs[16][68];
  const int tid = threadIdx.x;
  const int tx = tid & 15, ty = tid >> 4;
  const int m0 = blockIdx.y * 64, n0 = blockIdx.x * 64;
  float acc[8][4] = {};
  for (int k0 = 0; k0 < K; k0 += 16){
    #pragma unroll
    for (int r = 0; r < 2; ++r){
      int idx = tid + r*128;
      int mm = idx >> 2, kk4 = (idx & 3) * 4;
      float4 a = *(const float4*)&A[(size_t)(m0+mm)*K + k0 + kk4];
      as[kk4+0][mm] = a.x; as[kk4+1][mm] = a.y; as[kk4+2][mm] = a.z; as[kk4+3][mm] = a.w;
    }
    if (!BT){
      #pragma unroll
      for (int r = 0; r < 2; ++r){
        int idx = tid + r*128;
        int kk = idx >> 4, nn4 = (idx & 15) * 4;
        int n = n0 + nn4;
        float4 b = make_float4(0.f,0.f,0.f,0.f);
        if (n < N) b = *(const float4*)&B[(size_t)(k0+kk)*N + n];
        *(float4*)&bs[kk][nn4] = b;
      }
    } else {
      int nn = tid >> 1, kk8 = (tid & 1) * 8;
      int n = n0 + nn;
      float4 b0 = make_float4(0.f,0.f,0.f,0.f), b1 = b0;
      if (n < N){
        b0 = *(const float4*)&B[(size_t)n*K + k0 + kk8];
        b1 = *(const float4*)&B[(size_t)n*K + k0 + kk8 + 4];
      }
      bs[kk8+0][nn]=b0.x; bs[kk8+1][nn]=b0.y; bs[kk8+2][nn]=b0.z; bs[kk8+3][nn]=b0.w;
      bs[kk8+4][nn]=b1.x; bs[kk8+5][nn]=b1.y; bs[kk8+6][nn]=b1.z; bs[kk8+7][nn]=b1.w;
    }
    __syncthreads();
    #pragma unroll
    for (int kk = 0; kk < 16; ++kk){
      float ar[8], br[4];
      *(float4*)&ar[0] = *(const float4*)&as[kk][ty*4];
      *(float4*)&ar[4] = *(const float4*)&as[kk][32+ty*4];
      *(float4*)&br[0] = *(const float4*)&bs[kk][tx*4];
      #pragma unroll
      for (int i = 0; i < 8; ++i)
        #pragma unroll
        for (int j = 0; j < 4; ++j) acc[i][j] = fmaf(ar[i], br[j], acc[i][j]);
    }
    __syncthreads();
  }
  int n = n0 + tx*4;
  if (n < N){
    #pragma unroll
    for (int i = 0; i < 8; ++i){
      int row = m0 + ((i < 4) ? (ty*4 + i) : (32 + ty*4 + i - 4));
      float4 r; r.x=acc[i][0]; r.y=acc[i][1]; r.z=acc[i][2]; r.w=acc[i][3];
      *(float4*)&C[(size_t)row*N + n] = r;
    }
  }
}

// ---------------- causal depthwise conv + silu gating --------
__global__ void k_conv(const float* __restrict__ u, const float* __restrict__ g,
                       const float* __restrict__ cw, const float* __restrict__ cb,
                       float* __restrict__ hh){
  int idx = blockIdx.x*256 + threadIdx.x;  // over B*T*DIM
  int c  = idx % DIM;
  int bt = idx / DIM;
  int t  = bt % TT;
  float acc = cb[c];
  #pragma unroll
  for (int j = 0; j < KW; ++j){
    int dt_ = j - (KW-1);
    if (t + dt_ >= 0) acc = fmaf(u[(bt + dt_)*DIM + c], cw[c*KW + j], acc);
  }
  float h = siluf(acc);
  hh[idx] = siluf(g[idx]) * h;
}

// ---------------- pack small projection weights into (D, 28) ----------------
// cols: 0..3 gate(h) | 4..11 beta(m,h) | 12..19 alpha(m,h) | 20..27 blend(h*2+m)
__global__ void k_pack(const float* __restrict__ Wg, const float* __restrict__ Wb,
                       const float* __restrict__ Wa, const float* __restrict__ Wbl,
                       float* __restrict__ Wp){
  int d = blockIdx.x;     // 256
  int j = threadIdx.x;    // 32 (28 used)
  if (j >= 28) return;
  float v;
  if (j < 4)        v = Wg[d*HH + j];
  else if (j < 12){ int m=(j-4)>>2, h=(j-4)&3;  v = Wb[(m*DD + d)*HH + h]; }
  else if (j < 20){ int m=(j-12)>>2, h=(j-12)&3; v = Wa[(m*DD + d)*HH + h]; }
  else              v = Wbl[d*(HH*MM) + (j-20)];
  Wp[d*28 + j] = v;
}

// ---------------- rk normalization: unit-norm per (b,t,h) over 64 ----------
__global__ void k_rk(const float* __restrict__ y, float* __restrict__ rkb){
  int blk = blockIdx.x;          // B*T*H
  int lane = threadIdx.x;        // 64
  int row = blk >> 2, h = blk & 3;
  float v = y[row*DD + h*HDIM + lane];
  float ss = v*v;
  #pragma unroll
  for (int o = 32; o > 0; o >>= 1) ss += __shfl_xor(ss, o, 64);
  float nrm = fmaxf(sqrtf(ss), 1e-12f);
  rkb[row*DD + h*HDIM + lane] = v / nrm;
}

// ---------------- precompute scan scalars: dc, beta, blend*gate ----------
// scal layout: [row][m][h][4] = {dc, bt, bl*gs, 0}; row stride 32 floats.
__global__ void k_scal(const float* __restrict__ proj, const float* __restrict__ A_log,
                       const float* __restrict__ dtb, float* __restrict__ scal){
  int i = blockIdx.x*256 + threadIdx.x;   // over ROWS*MM*HH = 32768
  int mh = i & 7;
  int row = i >> 3;
  int m = mh >> 2, h = mh & 3;
  const float* pv = proj + (size_t)row*28;
  float gs  = sigf(pv[h]);
  float btv = sigf(pv[4 + m*4 + h]);
  float sp  = pv[12 + m*4 + h] + dtb[m*HH + h];
  sp = (sp > 15.f) ? sp : log1pf(__expf(sp));
  float dc  = __expf(-__expf(A_log[m*HH + h]) * sp);
  float l0 = pv[20 + h*2], l1 = pv[20 + h*2 + 1];
  float mx = fmaxf(l0, l1);
  float e0 = __expf(l0-mx), e1 = __expf(l1-mx);
  float bl = (m ? e1 : e0) / (e0 + e1);
  float4 o; o.x = dc; o.y = btv; o.z = bl*gs; o.w = 0.f;
  *(float4*)&scal[((size_t)row*MM + m)*(HH*4) + h*4] = o;
}

// ---------------- sequential delta-memory scan ----------
// grid = B*H*M*4 blocks (k-split by 4), 64 threads = 1 wave.
// lane = kl*4 + q: owns k = kq*16+kl, d in [q*16, q*16+16)  (S[16]/lane).
// d-reduces = xor1+xor2 DPP (pure VALU). Chunk-of-64 LDS staging via
// global_load_lds (double-buffered). rk(t+1)/v(t+1)/sc(t+1) prefetched into
// registers during step t, so no LDS latency on the serial chain.
// wk(t)=rk(t-1) via rkA/rkB register rotation (unroll-2).

#define SSTEP(TT_, WK, RK) { \
  const float dc = scpf.x, btv = scpf.y, blg = scpf.z; \
  const float v = vpf; \
  float pp0=0.f,pp1=0.f,pp2=0.f,pp3=0.f; \
  _Pragma("unroll") \
  for (int j = 0; j < 4; ++j){ const float4 r = WK[j]; \
    if (ROT == 0){ \
      pp0 = fmaf(S[4*j+0], r.x, pp0); pp1 = fmaf(S[4*j+1], r.y, pp1); \
      pp2 = fmaf(S[4*j+2], r.z, pp2); pp3 = fmaf(S[4*j+3], r.w, pp3); \
    } else { \
      pp0 = fmaf(S[4*j+0], -r.y, pp0); pp1 = fmaf(S[4*j+1], r.x, pp1); \
      pp2 = fmaf(S[4*j+2], -r.w, pp2); pp3 = fmaf(S[4*j+3], r.z, pp3); } } \
  float pp = (pp0+pp1)+(pp2+pp3); \
  pp = xor1_add(pp); pp = xor2_add(pp); \
  const float err = (v - dc*pp)*btv; \
  float rr0=0.f,rr1=0.f,rr2=0.f,rr3=0.f; \
  _Pragma("unroll") \
  for (int j = 0; j < 4; ++j){ const float4 rp = WK[j]; const float4 rc = RK[j]; \
    float w0,w1,w2,w3,c0,c1,c2,c3; \
    if (ROT == 0){ w0=rp.x; w1=rp.y; w2=rp.z; w3=rp.w; c0=rc.x; c1=rc.y; c2=rc.z; c3=rc.w; } \
    else { w0=-rp.y; w1=rp.x; w2=-rp.w; w3=rp.z; c0=-rc.y; c1=rc.x; c2=-rc.w; c3=rc.z; } \
    S[4*j+0] = fmaf(S[4*j+0], dc, w0*err); rr0 = fmaf(S[4*j+0], c0, rr0); \
    S[4*j+1] = fmaf(S[4*j+1], dc, w1*err); rr1 = fmaf(S[4*j+1], c1, rr1); \
    S[4*j+2] = fmaf(S[4*j+2], dc, w2*err); rr2 = fmaf(S[4*j+2], c2, rr2); \
    S[4*j+3] = fmaf(S[4*j+3], dc, w3*err); rr3 = fmaf(S[4*j+3], c3, rr3); } \
  float rr = (rr0+rr1)+(rr2+rr3); \
  rr = xor1_add(rr); rr = xor2_add(rr); \
  if (q == 0) part[(size_t)(rowchunk + (TT_))*DD + h*HDIM + kq*16 + kl] = blg*rr; \
  { const int tn = ((TT_)+1 < 64) ? (TT_)+1 : 63; /* clamped; harmless at 63 */ \
    _Pragma("unroll") \
    for (int j = 0; j < 4; ++j) WK[j] = *(const float4*)&s_rk[p][tn][dbase + 4*j]; \
    vpf = s_v[p][tn][kl]; \
    scpf = *(const float4*)&s_sc[p][tn][0]; } \
}

template<int ROT>
__device__ __forceinline__ void scan_body(int b, int h, int kq, int l,
    const float* __restrict__ vals, const float* __restrict__ rkb,
    const float* __restrict__ scal, float* __restrict__ part,
    float (*s_rk)[64][64], float (*s_v)[64][16], float (*s_sc)[64][4])
{
  const int q = l & 3, kl = l >> 2, dbase = q*16;
  const int rowbase = b*TT;

  float S[16];
  #pragma unroll
  for (int j = 0; j < 16; ++j) S[j] = 0.f;
  float4 rkA[4], rkB[4];
  #pragma unroll
  for (int j = 0; j < 4; ++j){ rkA[j].x=0.f; rkA[j].y=0.f; rkA[j].z=0.f; rkA[j].w=0.f; }

  auto stage = [&](int c, int pbuf){
    const int r0 = rowbase + c*64;
    #pragma unroll
    for (int i = 0; i < 16; ++i){
      const float* g = rkb + (size_t)(r0 + i*4 + (l>>4))*DD + h*HDIM + (l&15)*4;
      gl_lds16(g, &s_rk[pbuf][i*4][0]);
    }
    #pragma unroll
    for (int i = 0; i < 4; ++i){
      const float* g = vals + ((size_t)(r0 + i*16 + (l>>2))*MM + ROT)*DD + h*HDIM + kq*16 + (l&3)*4;
      gl_lds16(g, &s_v[pbuf][i*16][0]);
    }
    { const float* g = scal + ((size_t)(r0 + l)*MM + ROT)*(HH*4) + h*4;
      gl_lds16(g, &s_sc[pbuf][0][0]); }
  };

  stage(0, 0);
  float vpf = 0.f; float4 scpf = make_float4(0.f,0.f,0.f,0.f);
  for (int c = 0; c < TT/64; ++c){
    const int p = c & 1;
    __syncthreads();                 // vmcnt drain: chunk c staged
    if (c + 1 < TT/64) stage(c+1, p^1);
    // load step-0 operands of chunk c (rk(0)->rkB; rkA holds wk(0))
    #pragma unroll
    for (int j = 0; j < 4; ++j) rkB[j] = *(const float4*)&s_rk[p][0][dbase + 4*j];
    vpf = s_v[p][0][kl];
    scpf = *(const float4*)&s_sc[p][0][0];
    const int rowchunk = rowbase + c*64;
    for (int tt = 0; tt < 64; tt += 2){
      SSTEP(tt,   rkA, rkB)
      SSTEP(tt+1, rkB, rkA)
    }
  }
}

__global__ void __launch_bounds__(64) k_scan(const float* __restrict__ vals,
                                             const float* __restrict__ rkb,
                                             const float* __restrict__ scal,
                                             float* __restrict__ partials){
  __shared__ float s_rk[2][64][64];
  __shared__ float s_v [2][64][16];
  __shared__ float s_sc[2][64][4];
  const int bi = blockIdx.x;      // (((b*HH)+h)*MM + m)*4 + kq
  const int kq = bi & 3;
  const int m  = (bi >> 2) & 1;
  const int h  = (bi >> 3) & 3;
  const int b  = bi >> 5;
  float* part = partials + (size_t)m*(BB*TT*DD);
  if (m == 0) scan_body<0>(b, h, kq, threadIdx.x, vals, rkb, scal, part, s_rk, s_v, s_sc);
  else        scan_body<1>(b, h, kq, threadIdx.x, vals, rkb, scal, part, s_rk, s_v, s_sc);
}

// ---------------- combine partial outputs: o = p0 + p1 ----------------
__global__ void k_comb(const float* __restrict__ a, const float* __restrict__ b,
                       float* __restrict__ o){
  int i = blockIdx.x*256 + threadIdx.x;
  float4 x = ((const float4*)a)[i];
  float4 y = ((const float4*)b)[i];
  x.x += y.x; x.y += y.y; x.z += y.z; x.w += y.w;
  ((float4*)o)[i] = x;
}

// ---------------- residual: x += y + z ----------------
__global__ void k_resid(float* __restrict__ x, const float* __restrict__ y,
                        const float* __restrict__ z){
  int i = blockIdx.x*256 + threadIdx.x;
  float4* x4 = (float4*)x;
  const float4* y4 = (const float4*)y;
  const float4* z4 = (const float4*)z;
  float4 a = x4[i], bq = y4[i], c = z4[i];
  a.x += bq.x + c.x; a.y += bq.y + c.y; a.z += bq.z + c.z; a.w += bq.w + c.w;
  x4[i] = a;
}

extern "C" void kernel_launch(void* const* d_in, const int* in_sizes, int n_in,
                              void* d_out, int out_size, void* d_ws, size_t ws_size,
                              hipStream_t stream){
  const int*   ids   = (const int*)d_in[0];
  const float* emb   = (const float*)d_in[1];
  const float* normw = (const float*)d_in[2];
  const float* Wup   = (const float*)d_in[3];
  const float* Wgate = (const float*)d_in[4];
  const float* Wdown = (const float*)d_in[5];
  const float* convw = (const float*)d_in[6];
  const float* convb = (const float*)d_in[7];
  const float* Wv    = (const float*)d_in[8];
  const float* Wg    = (const float*)d_in[9];
  const float* Wb    = (const float*)d_in[10];
  const float* Wa    = (const float*)d_in[11];
  const float* A_log = (const float*)d_in[12];
  const float* dtb   = (const float*)d_in[13];
  const float* Wbl   = (const float*)d_in[14];
  const float* Wout  = (const float*)d_in[15];
  const float* fnw   = (const float*)d_in[16];
  float* out = (float*)d_out;

  const int ROWS = BB*TT;              // 4096
  const size_t MEG = 1u << 20;         // 1,048,576 floats
  float* ws   = (float*)d_ws;
  float* x    = ws;                    // 1M
  float* nx   = x    + MEG;            // 1M
  float* big1 = nx   + MEG;            // 2M : u, then vals, then obuf
  float* big2 = big1 + 2*MEG;          // 2M : g/hh, then partials, then z
  float* y    = big2 + 2*MEG;          // 1M
  float* proj = y    + MEG;            // 128K
  float* rkb  = proj + (1u<<17);       // 1M
  float* Wp   = rkb  + MEG;            // 8K
  float* scal = Wp   + 8192;           // 128K

  k_embed<<<ROWS, DD, 0, stream>>>(ids, emb, x);

  for (int l = 0; l < LL; ++l){
    k_rmsnorm<<<ROWS, 64, 0, stream>>>(x, normw + l*DD, nx);
    float* u = big1; float* g = big2;
    k_gemm<false><<<dim3(DIM/64, ROWS/64), 128, 0, stream>>>(nx, Wup + (size_t)l*DD*DIM, u, DIM, DD);
    k_gemm<false><<<dim3(DIM/64, ROWS/64), 128, 0, stream>>>(nx, Wgate + (size_t)l*DD*DIM, g, DIM, DD);
    k_conv<<<(ROWS*DIM)/256, 256, 0, stream>>>(u, g, convw + l*DIM*KW, convb + l*DIM, g);
    k_gemm<false><<<dim3(DD/64, ROWS/64), 128, 0, stream>>>(g, Wdown + (size_t)l*DIM*DD, y, DD, DIM);
    float* vals = big1;
    k_gemm<false><<<dim3((MM*DD)/64, ROWS/64), 128, 0, stream>>>(y, Wv + (size_t)l*DD*MM*DD, vals, MM*DD, DD);
    k_pack<<<DD, 32, 0, stream>>>(Wg + l*DD*HH, Wb + l*MM*DD*HH, Wa + l*MM*DD*HH,
                                  Wbl + l*DD*HH*MM, Wp);
    k_gemm<false><<<dim3(1, ROWS/64), 128, 0, stream>>>(y, Wp, proj, 28, DD);
    k_scal<<<(ROWS*MM*HH)/256, 256, 0, stream>>>(proj, A_log + l*MM*HH, dtb + l*MM*HH, scal);
    k_rk<<<ROWS*HH, 64, 0, stream>>>(y, rkb);
    // scan: partials in big2 (2 x 1M), vals still in big1
    k_scan<<<BB*HH*MM*4, 64, 0, stream>>>(vals, rkb, scal, big2);
    // combine into big1 (vals dead now)
    float* obuf = big1;
    k_comb<<<(ROWS*DD/4)/256, 256, 0, stream>>>(big2, big2 + MEG, obuf);
    float* z = big2;   // overwrite partial0
    k_gemm<false><<<dim3(DD/64, ROWS/64), 128, 0, stream>>>(obuf, Wout + (size_t)l*DD*DD, z, DD, DD);
    k_resid<<<(ROWS*DD)/1024, 256, 0, stream>>>(x, y, z);
  }

  k_rmsnorm<<<ROWS, 64, 0, stream>>>(x, fnw, nx);
  k_gemm<true><<<dim3((VV+63)/64, ROWS/64), 128, 0, stream>>>(nx, emb, out, VV, DD);
}

// Round 6
// 451.519 us; speedup vs baseline: 8.1690x; 1.7017x over previous
//
#include <hip/hip_runtime.h>
#include <math.h>

#define BB 8
#define TT 512
#define DD 256
#define DIM 512
#define KW 4
#define MM 2
#define HH 4
#define HDIM 64
#define LL 2
#define VV 272

typedef __attribute__((ext_vector_type(8))) short bf16x8;
typedef __attribute__((ext_vector_type(4))) float f32x4;

__device__ __forceinline__ float sigf(float x){ return 1.f/(1.f+__expf(-x)); }
__device__ __forceinline__ float siluf(float x){ return x/(1.f+__expf(-x)); }

__device__ __forceinline__ unsigned short f2bf(float f){
  unsigned int u = __float_as_uint(f);
  unsigned int r = (u + 0x7FFFu + ((u >> 16) & 1u)) >> 16;
  return (unsigned short)r;
}

// lane^1 and lane^2 reduces via DPP quad_perm — pure VALU, no DS ops.
__device__ __forceinline__ float xor1_add(float x){
  int y = __builtin_amdgcn_update_dpp(0, __float_as_int(x), 0xB1, 0xF, 0xF, true);
  return x + __int_as_float(y);
}
__device__ __forceinline__ float xor2_add(float x){
  int y = __builtin_amdgcn_update_dpp(0, __float_as_int(x), 0x4E, 0xF, 0xF, true);
  return x + __int_as_float(y);
}

// async global->LDS, 16B per lane. LDS dest is wave-uniform base + lane*16.
__device__ __forceinline__ void gl_lds16(const float* g, float* l){
  __builtin_amdgcn_global_load_lds(
      (const __attribute__((address_space(1))) unsigned int*)g,
      (__attribute__((address_space(3))) unsigned int*)l,
      16, 0, 0);
}

// ---------------- embedding gather ----------------
__global__ void k_embed(const int* __restrict__ ids, const float* __restrict__ emb,
                        float* __restrict__ x){
  int row = blockIdx.x;
  int d = threadIdx.x;
  x[row*DD + d] = emb[ids[row]*DD + d];
}

// ---------------- rmsnorm (row of 256), 1 wave/row ----------------
__global__ void k_rmsnorm(const float* __restrict__ in, const float* __restrict__ w,
                          float* __restrict__ out){
  int row = blockIdx.x;
  int l = threadIdx.x;             // 64
  float4 v = *(const float4*)&in[row*DD + l*4];
  float ss = v.x*v.x + v.y*v.y + v.z*v.z + v.w*v.w;
  #pragma unroll
  for (int o = 32; o > 0; o >>= 1) ss += __shfl_xor(ss, o, 64);
  float sc = rsqrtf(ss*(1.f/DD) + 1e-6f);
  float4 wv = *(const float4*)&w[l*4];
  float4 r;
  r.x = v.x*sc*wv.x; r.y = v.y*sc*wv.y; r.z = v.z*sc*wv.z; r.w = v.w*sc*wv.w;
  *(float4*)&out[row*DD + l*4] = r;
}

// ---------------- bf16 MFMA GEMM: C[4096,N] = A[4096,K] @ B ----------------
// 64x64 tile, 256 threads (4 waves), BK=64. f32 inputs cast to bf16 (RNE)
// during LDS staging. Frag layouts (verified m89/m91):
//  A: lane l holds A[m=l&15][(l>>4)*8 + j], j=0..7 (contiguous k)
//  B: lane l holds B[(l>>4)*8 + j][n=l&15]  -> stage B as [col][k]
//  D: col = l&15, row = (l>>4)*4 + reg
// BT=false: B is (K,N) row-major.  BT=true: B is (N,K) row-major (C = A @ B^T).
template<bool BT>
__global__ void __launch_bounds__(256) k_gemm_bf(const float* __restrict__ A,
                                                 const float* __restrict__ B,
                                                 float* __restrict__ C, int N, int K){
  __shared__ unsigned short as[64][88];   // [row][k], stride 176B (16B-aligned)
  __shared__ unsigned short bs[64][88];   // [col][k]
  const int tid = threadIdx.x;
  const int w = tid >> 6, l = tid & 63;
  const int m0 = blockIdx.y*64, n0 = blockIdx.x*64;
  f32x4 acc[4] = {};
  for (int k0 = 0; k0 < K; k0 += 64){
    { // stage A: 64 rows x 64 k
      int ar = tid >> 2, ac = (tid & 3)*16;
      #pragma unroll
      for (int j = 0; j < 4; ++j){
        float4 a = *(const float4*)&A[(size_t)(m0+ar)*K + k0 + ac + j*4];
        ushort4 u = make_ushort4(f2bf(a.x), f2bf(a.y), f2bf(a.z), f2bf(a.w));
        *(ushort4*)&as[ar][ac + j*4] = u;
      }
    }
    if (!BT){ // B[K][N] -> bs[col][k] (scatter)
      int kr = tid >> 2, nc = (tid & 3)*16;
      #pragma unroll
      for (int j = 0; j < 4; ++j){
        int n = n0 + nc + j*4;
        float4 bv = make_float4(0.f,0.f,0.f,0.f);
        if (n < N) bv = *(const float4*)&B[(size_t)(k0+kr)*N + n];
        bs[nc+j*4+0][kr] = f2bf(bv.x);
        bs[nc+j*4+1][kr] = f2bf(bv.y);
        bs[nc+j*4+2][kr] = f2bf(bv.z);
        bs[nc+j*4+3][kr] = f2bf(bv.w);
      }
    } else {  // B[N][K] -> bs[col][k] (direct)
      int nr = tid >> 2, kc = (tid & 3)*16;
      int n = n0 + nr;
      #pragma unroll
      for (int j = 0; j < 4; ++j){
        float4 bv = make_float4(0.f,0.f,0.f,0.f);
        if (n < N) bv = *(const float4*)&B[(size_t)n*K + k0 + kc + j*4];
        ushort4 u = make_ushort4(f2bf(bv.x), f2bf(bv.y), f2bf(bv.z), f2bf(bv.w));
        *(ushort4*)&bs[nr][kc + j*4] = u;
      }
    }
    __syncthreads();
    const int mr = w*16 + (l & 15);
    const int kb = (l >> 4)*8;
    #pragma unroll
    for (int kc2 = 0; kc2 < 2; ++kc2){
      bf16x8 af = *(const bf16x8*)&as[mr][kc2*32 + kb];
      #pragma unroll
      for (int nt = 0; nt < 4; ++nt){
        bf16x8 bfr = *(const bf16x8*)&bs[nt*16 + (l & 15)][kc2*32 + kb];
        acc[nt] = __builtin_amdgcn_mfma_f32_16x16x32_bf16(af, bfr, acc[nt], 0, 0, 0);
      }
    }
    __syncthreads();
  }
  #pragma unroll
  for (int nt = 0; nt < 4; ++nt){
    int col = n0 + nt*16 + (l & 15);
    if (col < N){
      #pragma unroll
      for (int r = 0; r < 4; ++r){
        int row = m0 + w*16 + (l >> 4)*4 + r;
        C[(size_t)row*N + col] = acc[nt][r];
      }
    }
  }
}

// ---------------- f32 GEMM (small-N path, proj only) ----------------
template<bool BT>
__global__ void __launch_bounds__(128) k_gemm(const float* __restrict__ A,
                                              const float* __restrict__ B,
                                              float* __restrict__ C, int N, int K){
  __shared__ float as[16][68];
  __shared__ float bs[16][68];
  const int tid = threadIdx.x;
  const int tx = tid & 15, ty = tid >> 4;
  const int m0 = blockIdx.y * 64, n0 = blockIdx.x * 64;
  float acc[8][4] = {};
  for (int k0 = 0; k0 < K; k0 += 16){
    #pragma unroll
    for (int r = 0; r < 2; ++r){
      int idx = tid + r*128;
      int mm = idx >> 2, kk4 = (idx & 3) * 4;
      float4 a = *(const float4*)&A[(size_t)(m0+mm)*K + k0 + kk4];
      as[kk4+0][mm] = a.x; as[kk4+1][mm] = a.y; as[kk4+2][mm] = a.z; as[kk4+3][mm] = a.w;
    }
    if (!BT){
      #pragma unroll
      for (int r = 0; r < 2; ++r){
        int idx = tid + r*128;
        int kk = idx >> 4, nn4 = (idx & 15) * 4;
        int n = n0 + nn4;
        float4 b = make_float4(0.f,0.f,0.f,0.f);
        if (n < N) b = *(const float4*)&B[(size_t)(k0+kk)*N + n];
        *(float4*)&bs[kk][nn4] = b;
      }
    } else {
      int nn = tid >> 1, kk8 = (tid & 1) * 8;
      int n = n0 + nn;
      float4 b0 = make_float4(0.f,0.f,0.f,0.f), b1 = b0;
      if (n < N){
        b0 = *(const float4*)&B[(size_t)n*K + k0 + kk8];
        b1 = *(const float4*)&B[(size_t)n*K + k0 + kk8 + 4];
      }
      bs[kk8+0][nn]=b0.x; bs[kk8+1][nn]=b0.y; bs[kk8+2][nn]=b0.z; bs[kk8+3][nn]=b0.w;
      bs[kk8+4][nn]=b1.x; bs[kk8+5][nn]=b1.y; bs[kk8+6][nn]=b1.z; bs[kk8+7][nn]=b1.w;
    }
    __syncthreads();
    #pragma unroll
    for (int kk = 0; kk < 16; ++kk){
      float ar[8], br[4];
      *(float4*)&ar[0] = *(const float4*)&as[kk][ty*4];
      *(float4*)&ar[4] = *(const float4*)&as[kk][32+ty*4];
      *(float4*)&br[0] = *(const float4*)&bs[kk][tx*4];
      #pragma unroll
      for (int i = 0; i < 8; ++i)
        #pragma unroll
        for (int j = 0; j < 4; ++j) acc[i][j] = fmaf(ar[i], br[j], acc[i][j]);
    }
    __syncthreads();
  }
  int n = n0 + tx*4;
  if (n < N){
    #pragma unroll
    for (int i = 0; i < 8; ++i){
      int row = m0 + ((i < 4) ? (ty*4 + i) : (32 + ty*4 + i - 4));
      float4 r; r.x=acc[i][0]; r.y=acc[i][1]; r.z=acc[i][2]; r.w=acc[i][3];
      *(float4*)&C[(size_t)row*N + n] = r;
    }
  }
}

// ---------------- causal depthwise conv + silu gating --------
__global__ void k_conv(const float* __restrict__ u, const float* __restrict__ g,
                       const float* __restrict__ cw, const float* __restrict__ cb,
                       float* __restrict__ hh){
  int idx = blockIdx.x*256 + threadIdx.x;
  int c  = idx % DIM;
  int bt = idx / DIM;
  int t  = bt % TT;
  float acc = cb[c];
  #pragma unroll
  for (int j = 0; j < KW; ++j){
    int dt_ = j - (KW-1);
    if (t + dt_ >= 0) acc = fmaf(u[(bt + dt_)*DIM + c], cw[c*KW + j], acc);
  }
  float h = siluf(acc);
  hh[idx] = siluf(g[idx]) * h;
}

// ---------------- pack small projection weights into (D, 28) ----------------
__global__ void k_pack(const float* __restrict__ Wg, const float* __restrict__ Wb,
                       const float* __restrict__ Wa, const float* __restrict__ Wbl,
                       float* __restrict__ Wp){
  int d = blockIdx.x;
  int j = threadIdx.x;
  if (j >= 28) return;
  float v;
  if (j < 4)        v = Wg[d*HH + j];
  else if (j < 12){ int m=(j-4)>>2, h=(j-4)&3;  v = Wb[(m*DD + d)*HH + h]; }
  else if (j < 20){ int m=(j-12)>>2, h=(j-12)&3; v = Wa[(m*DD + d)*HH + h]; }
  else              v = Wbl[d*(HH*MM) + (j-20)];
  Wp[d*28 + j] = v;
}

// ---------------- rk normalization ----------
__global__ void k_rk(const float* __restrict__ y, float* __restrict__ rkb){
  int blk = blockIdx.x;
  int lane = threadIdx.x;
  int row = blk >> 2, h = blk & 3;
  float v = y[row*DD + h*HDIM + lane];
  float ss = v*v;
  #pragma unroll
  for (int o = 32; o > 0; o >>= 1) ss += __shfl_xor(ss, o, 64);
  float nrm = fmaxf(sqrtf(ss), 1e-12f);
  rkb[row*DD + h*HDIM + lane] = v / nrm;
}

// ---------------- precompute scan scalars ----------
__global__ void k_scal(const float* __restrict__ proj, const float* __restrict__ A_log,
                       const float* __restrict__ dtb, float* __restrict__ scal){
  int i = blockIdx.x*256 + threadIdx.x;
  int mh = i & 7;
  int row = i >> 3;
  int m = mh >> 2, h = mh & 3;
  const float* pv = proj + (size_t)row*28;
  float gs  = sigf(pv[h]);
  float btv = sigf(pv[4 + m*4 + h]);
  float sp  = pv[12 + m*4 + h] + dtb[m*HH + h];
  sp = (sp > 15.f) ? sp : log1pf(__expf(sp));
  float dc  = __expf(-__expf(A_log[m*HH + h]) * sp);
  float l0 = pv[20 + h*2], l1 = pv[20 + h*2 + 1];
  float mx = fmaxf(l0, l1);
  float e0 = __expf(l0-mx), e1 = __expf(l1-mx);
  float bl = (m ? e1 : e0) / (e0 + e1);
  float4 o; o.x = dc; o.y = btv; o.z = bl*gs; o.w = 0.f;
  *(float4*)&scal[((size_t)row*MM + m)*(HH*4) + h*4] = o;
}

// ---------------- sequential delta-memory scan ----------
// grid = B*H*M*4 blocks (k-split by 4), 64 threads = 1 wave.
// lane = kl*4 + q: owns k = kq*16+kl, d in [q*16, q*16+16)  (S[16]/lane).
// Depth-2 prefetch: v/sc double-buffered 2 steps ahead; rk in a period-4
// register rotation (rk(t+2) loaded during step t) -> no LDS latency on chain.

#define SSTEP(T_, WK, RK, PF, VB, SB) { \
  const float dc = SB.x, btv = SB.y, blg = SB.z; \
  const float v = VB; \
  float pp0=0.f,pp1=0.f,pp2=0.f,pp3=0.f; \
  _Pragma("unroll") \
  for (int j = 0; j < 4; ++j){ const float4 r = WK[j]; \
    if (ROT == 0){ \
      pp0 = fmaf(S[4*j+0], r.x, pp0); pp1 = fmaf(S[4*j+1], r.y, pp1); \
      pp2 = fmaf(S[4*j+2], r.z, pp2); pp3 = fmaf(S[4*j+3], r.w, pp3); \
    } else { \
      pp0 = fmaf(S[4*j+0], -r.y, pp0); pp1 = fmaf(S[4*j+1], r.x, pp1); \
      pp2 = fmaf(S[4*j+2], -r.w, pp2); pp3 = fmaf(S[4*j+3], r.z, pp3); } } \
  float pp = (pp0+pp1)+(pp2+pp3); \
  pp = xor1_add(pp); pp = xor2_add(pp); \
  const float err = (v - dc*pp)*btv; \
  float rr0=0.f,rr1=0.f,rr2=0.f,rr3=0.f; \
  _Pragma("unroll") \
  for (int j = 0; j < 4; ++j){ const float4 rp = WK[j]; const float4 rc = RK[j]; \
    float w0,w1,w2,w3,c0,c1,c2,c3; \
    if (ROT == 0){ w0=rp.x; w1=rp.y; w2=rp.z; w3=rp.w; c0=rc.x; c1=rc.y; c2=rc.z; c3=rc.w; } \
    else { w0=-rp.y; w1=rp.x; w2=-rp.w; w3=rp.z; c0=-rc.y; c1=rc.x; c2=-rc.w; c3=rc.z; } \
    S[4*j+0] = fmaf(S[4*j+0], dc, w0*err); rr0 = fmaf(S[4*j+0], c0, rr0); \
    S[4*j+1] = fmaf(S[4*j+1], dc, w1*err); rr1 = fmaf(S[4*j+1], c1, rr1); \
    S[4*j+2] = fmaf(S[4*j+2], dc, w2*err); rr2 = fmaf(S[4*j+2], c2, rr2); \
    S[4*j+3] = fmaf(S[4*j+3], dc, w3*err); rr3 = fmaf(S[4*j+3], c3, rr3); } \
  float rr = (rr0+rr1)+(rr2+rr3); \
  rr = xor1_add(rr); rr = xor2_add(rr); \
  if (q == 0) part[(size_t)(rowchunk + (T_))*DD + h*HDIM + kq*16 + kl] = blg*rr; \
  { const int tn_ = ((T_)+2 < 64) ? (T_)+2 : 63; \
    _Pragma("unroll") \
    for (int j = 0; j < 4; ++j) PF[j] = *(const float4*)&s_rk[p][tn_][dbase + 4*j]; \
    VB = s_v[p][tn_][kl]; \
    SB = *(const float4*)&s_sc[p][tn_][0]; } \
}

template<int ROT>
__device__ __forceinline__ void scan_body(int b, int h, int kq, int l,
    const float* __restrict__ vals, const float* __restrict__ rkb,
    const float* __restrict__ scal, float* __restrict__ part,
    float (*s_rk)[64][64], float (*s_v)[64][16], float (*s_sc)[64][4])
{
  const int q = l & 3, kl = l >> 2, dbase = q*16;
  const int rowbase = b*TT;

  float S[16];
  #pragma unroll
  for (int j = 0; j < 16; ++j) S[j] = 0.f;
  float4 rb0[4], rb1[4], rb2[4], rb3[4];
  #pragma unroll
  for (int j = 0; j < 4; ++j){
    rb0[j]=make_float4(0.f,0.f,0.f,0.f); rb1[j]=rb0[j]; rb2[j]=rb0[j]; rb3[j]=rb0[j];
  }

  auto stage = [&](int c, int pbuf){
    const int r0 = rowbase + c*64;
    #pragma unroll
    for (int i = 0; i < 16; ++i){
      const float* g = rkb + (size_t)(r0 + i*4 + (l>>4))*DD + h*HDIM + (l&15)*4;
      gl_lds16(g, &s_rk[pbuf][i*4][0]);
    }
    #pragma unroll
    for (int i = 0; i < 4; ++i){
      const float* g = vals + ((size_t)(r0 + i*16 + (l>>2))*MM + ROT)*DD + h*HDIM + kq*16 + (l&3)*4;
      gl_lds16(g, &s_v[pbuf][i*16][0]);
    }
    { const float* g = scal + ((size_t)(r0 + l)*MM + ROT)*(HH*4) + h*4;
      gl_lds16(g, &s_sc[pbuf][0][0]); }
  };

  stage(0, 0);
  float vb0 = 0.f, vb1 = 0.f;
  float4 sb0 = make_float4(0.f,0.f,0.f,0.f), sb1 = sb0;
  for (int c = 0; c < TT/64; ++c){
    const int p = c & 1;
    __syncthreads();                 // vmcnt drain: chunk c staged
    if (c + 1 < TT/64) stage(c+1, p^1);
    // prologue: rk(0)->rb0, rk(1)->rb1; v/sc for steps 0,1.
    // rb3 carries wk(0) = rk(63 of prev chunk) (zeros for chunk 0).
    #pragma unroll
    for (int j = 0; j < 4; ++j) rb0[j] = *(const float4*)&s_rk[p][0][dbase + 4*j];
    #pragma unroll
    for (int j = 0; j < 4; ++j) rb1[j] = *(const float4*)&s_rk[p][1][dbase + 4*j];
    vb0 = s_v[p][0][kl]; vb1 = s_v[p][1][kl];
    sb0 = *(const float4*)&s_sc[p][0][0]; sb1 = *(const float4*)&s_sc[p][1][0];
    const int rowchunk = rowbase + c*64;
    for (int tt = 0; tt < 64; tt += 4){
      SSTEP(tt,   rb3, rb0, rb2, vb0, sb0)
      SSTEP(tt+1, rb0, rb1, rb3, vb1, sb1)
      SSTEP(tt+2, rb1, rb2, rb0, vb0, sb0)
      SSTEP(tt+3, rb2, rb3, rb1, vb1, sb1)
    }
  }
}

__global__ void __launch_bounds__(64) k_scan(const float* __restrict__ vals,
                                             const float* __restrict__ rkb,
                                             const float* __restrict__ scal,
                                             float* __restrict__ partials){
  __shared__ float s_rk[2][64][64];
  __shared__ float s_v [2][64][16];
  __shared__ float s_sc[2][64][4];
  const int bi = blockIdx.x;      // (((b*HH)+h)*MM + m)*4 + kq
  const int kq = bi & 3;
  const int m  = (bi >> 2) & 1;
  const int h  = (bi >> 3) & 3;
  const int b  = bi >> 5;
  float* part = partials + (size_t)m*(BB*TT*DD);
  if (m == 0) scan_body<0>(b, h, kq, threadIdx.x, vals, rkb, scal, part, s_rk, s_v, s_sc);
  else        scan_body<1>(b, h, kq, threadIdx.x, vals, rkb, scal, part, s_rk, s_v, s_sc);
}

// ---------------- combine partial outputs ----------------
__global__ void k_comb(const float* __restrict__ a, const float* __restrict__ b,
                       float* __restrict__ o){
  int i = blockIdx.x*256 + threadIdx.x;
  float4 x = ((const float4*)a)[i];
  float4 y = ((const float4*)b)[i];
  x.x += y.x; x.y += y.y; x.z += y.z; x.w += y.w;
  ((float4*)o)[i] = x;
}

// ---------------- residual: x += y + z ----------------
__global__ void k_resid(float* __restrict__ x, const float* __restrict__ y,
                        const float* __restrict__ z){
  int i = blockIdx.x*256 + threadIdx.x;
  float4* x4 = (float4*)x;
  const float4* y4 = (const float4*)y;
  const float4* z4 = (const float4*)z;
  float4 a = x4[i], bq = y4[i], c = z4[i];
  a.x += bq.x + c.x; a.y += bq.y + c.y; a.z += bq.z + c.z; a.w += bq.w + c.w;
  x4[i] = a;
}

extern "C" void kernel_launch(void* const* d_in, const int* in_sizes, int n_in,
                              void* d_out, int out_size, void* d_ws, size_t ws_size,
                              hipStream_t stream){
  const int*   ids   = (const int*)d_in[0];
  const float* emb   = (const float*)d_in[1];
  const float* normw = (const float*)d_in[2];
  const float* Wup   = (const float*)d_in[3];
  const float* Wgate = (const float*)d_in[4];
  const float* Wdown = (const float*)d_in[5];
  const float* convw = (const float*)d_in[6];
  const float* convb = (const float*)d_in[7];
  const float* Wv    = (const float*)d_in[8];
  const float* Wg    = (const float*)d_in[9];
  const float* Wb    = (const float*)d_in[10];
  const float* Wa    = (const float*)d_in[11];
  const float* A_log = (const float*)d_in[12];
  const float* dtb   = (const float*)d_in[13];
  const float* Wbl   = (const float*)d_in[14];
  const float* Wout  = (const float*)d_in[15];
  const float* fnw   = (const float*)d_in[16];
  float* out = (float*)d_out;

  const int ROWS = BB*TT;              // 4096
  const size_t MEG = 1u << 20;
  float* ws   = (float*)d_ws;
  float* x    = ws;                    // 1M
  float* nx   = x    + MEG;            // 1M
  float* big1 = nx   + MEG;            // 2M : u, then vals, then obuf
  float* big2 = big1 + 2*MEG;          // 2M : g/hh, then partials, then z
  float* y    = big2 + 2*MEG;          // 1M
  float* proj = y    + MEG;            // 128K
  float* rkb  = proj + (1u<<17);       // 1M
  float* Wp   = rkb  + MEG;            // 8K
  float* scal = Wp   + 8192;           // 128K

  k_embed<<<ROWS, DD, 0, stream>>>(ids, emb, x);

  for (int l = 0; l < LL; ++l){
    k_rmsnorm<<<ROWS, 64, 0, stream>>>(x, normw + l*DD, nx);
    float* u = big1; float* g = big2;
    k_gemm_bf<false><<<dim3(DIM/64, ROWS/64), 256, 0, stream>>>(nx, Wup + (size_t)l*DD*DIM, u, DIM, DD);
    k_gemm_bf<false><<<dim3(DIM/64, ROWS/64), 256, 0, stream>>>(nx, Wgate + (size_t)l*DD*DIM, g, DIM, DD);
    k_conv<<<(ROWS*DIM)/256, 256, 0, stream>>>(u, g, convw + l*DIM*KW, convb + l*DIM, g);
    k_gemm_bf<false><<<dim3(DD/64, ROWS/64), 256, 0, stream>>>(g, Wdown + (size_t)l*DIM*DD, y, DD, DIM);
    float* vals = big1;
    k_gemm_bf<false><<<dim3((MM*DD)/64, ROWS/64), 256, 0, stream>>>(y, Wv + (size_t)l*DD*MM*DD, vals, MM*DD, DD);
    k_pack<<<DD, 32, 0, stream>>>(Wg + l*DD*HH, Wb + l*MM*DD*HH, Wa + l*MM*DD*HH,
                                  Wbl + l*DD*HH*MM, Wp);
    k_gemm<false><<<dim3(1, ROWS/64), 128, 0, stream>>>(y, Wp, proj, 28, DD);
    k_scal<<<(ROWS*MM*HH)/256, 256, 0, stream>>>(proj, A_log + l*MM*HH, dtb + l*MM*HH, scal);
    k_rk<<<ROWS*HH, 64, 0, stream>>>(y, rkb);
    k_scan<<<BB*HH*MM*4, 64, 0, stream>>>(vals, rkb, scal, big2);
    float* obuf = big1;
    k_comb<<<(ROWS*DD/4)/256, 256, 0, stream>>>(big2, big2 + MEG, obuf);
    float* z = big2;
    k_gemm_bf<false><<<dim3(DD/64, ROWS/64), 256, 0, stream>>>(obuf, Wout + (size_t)l*DD*DD, z, DD, DD);
    k_resid<<<(ROWS*DD)/1024, 256, 0, stream>>>(x, y, z);
  }

  k_rmsnorm<<<ROWS, 64, 0, stream>>>(x, fnw, nx);
  k_gemm_bf<true><<<dim3((VV+63)/64, ROWS/64), 256, 0, stream>>>(nx, emb, out, VV, DD);
}

// Round 7
// 425.643 us; speedup vs baseline: 8.6656x; 1.0608x over previous
//
#include <hip/hip_runtime.h>
#include <math.h>

#define BB 8
#define TT 512
#define DD 256
#define DIM 512
#define KW 4
#define MM 2
#define HH 4
#define HDIM 64
#define LL 2
#define VV 272

typedef __attribute__((ext_vector_type(8))) short bf16x8;
typedef __attribute__((ext_vector_type(4))) float f32x4;

__device__ __forceinline__ float sigf(float x){ return 1.f/(1.f+__expf(-x)); }
__device__ __forceinline__ float siluf(float x){ return x/(1.f+__expf(-x)); }

__device__ __forceinline__ unsigned short f2bf(float f){
  unsigned int u = __float_as_uint(f);
  unsigned int r = (u + 0x7FFFu + ((u >> 16) & 1u)) >> 16;
  return (unsigned short)r;
}

// d-reduce via DPP only (no DS ops): xor1/xor2 = quad_perm, xor8 = row_ror:8
// (involution on l <-> l^8 within a 16-lane row).
__device__ __forceinline__ float xor1_add(float x){
  int y = __builtin_amdgcn_update_dpp(0, __float_as_int(x), 0xB1, 0xF, 0xF, true);
  return x + __int_as_float(y);
}
__device__ __forceinline__ float xor2_add(float x){
  int y = __builtin_amdgcn_update_dpp(0, __float_as_int(x), 0x4E, 0xF, 0xF, true);
  return x + __int_as_float(y);
}
__device__ __forceinline__ float xor8_add(float x){
  int y = __builtin_amdgcn_update_dpp(0, __float_as_int(x), 0x128, 0xF, 0xF, true);
  return x + __int_as_float(y);
}

// async global->LDS, 16B per lane. LDS dest is wave-uniform base + lane*16.
__device__ __forceinline__ void gl_lds16(const float* g, float* l){
  __builtin_amdgcn_global_load_lds(
      (const __attribute__((address_space(1))) unsigned int*)g,
      (__attribute__((address_space(3))) unsigned int*)l,
      16, 0, 0);
}

// ---------------- embedding gather ----------------
__global__ void k_embed(const int* __restrict__ ids, const float* __restrict__ emb,
                        float* __restrict__ x){
  int row = blockIdx.x;
  int d = threadIdx.x;
  x[row*DD + d] = emb[ids[row]*DD + d];
}

// ---------------- rmsnorm (row of 256), 1 wave/row ----------------
__global__ void k_rmsnorm(const float* __restrict__ in, const float* __restrict__ w,
                          float* __restrict__ out){
  int row = blockIdx.x;
  int l = threadIdx.x;             // 64
  float4 v = *(const float4*)&in[row*DD + l*4];
  float ss = v.x*v.x + v.y*v.y + v.z*v.z + v.w*v.w;
  #pragma unroll
  for (int o = 32; o > 0; o >>= 1) ss += __shfl_xor(ss, o, 64);
  float sc = rsqrtf(ss*(1.f/DD) + 1e-6f);
  float4 wv = *(const float4*)&w[l*4];
  float4 r;
  r.x = v.x*sc*wv.x; r.y = v.y*sc*wv.y; r.z = v.z*sc*wv.z; r.w = v.w*sc*wv.w;
  *(float4*)&out[row*DD + l*4] = r;
}

// ---------------- bf16 MFMA GEMM: C[4096,N] = A[4096,K] @ B ----------------
// 64x64 tile, 256 threads (4 waves), BK=64. f32 -> bf16 RNE during staging.
//  A: lane l holds A[m=l&15][(l>>4)*8 + j]   B: lane l holds B[(l>>4)*8+j][n=l&15]
//  D: col = l&15, row = (l>>4)*4 + reg
template<bool BT>
__global__ void __launch_bounds__(256) k_gemm_bf(const float* __restrict__ A,
                                                 const float* __restrict__ B,
                                                 float* __restrict__ C, int N, int K){
  __shared__ unsigned short as[64][88];
  __shared__ unsigned short bs[64][88];
  const int tid = threadIdx.x;
  const int w = tid >> 6, l = tid & 63;
  const int m0 = blockIdx.y*64, n0 = blockIdx.x*64;
  f32x4 acc[4] = {};
  for (int k0 = 0; k0 < K; k0 += 64){
    { int ar = tid >> 2, ac = (tid & 3)*16;
      #pragma unroll
      for (int j = 0; j < 4; ++j){
        float4 a = *(const float4*)&A[(size_t)(m0+ar)*K + k0 + ac + j*4];
        ushort4 u = make_ushort4(f2bf(a.x), f2bf(a.y), f2bf(a.z), f2bf(a.w));
        *(ushort4*)&as[ar][ac + j*4] = u;
      }
    }
    if (!BT){
      int kr = tid >> 2, nc = (tid & 3)*16;
      #pragma unroll
      for (int j = 0; j < 4; ++j){
        int n = n0 + nc + j*4;
        float4 bv = make_float4(0.f,0.f,0.f,0.f);
        if (n < N) bv = *(const float4*)&B[(size_t)(k0+kr)*N + n];
        bs[nc+j*4+0][kr] = f2bf(bv.x);
        bs[nc+j*4+1][kr] = f2bf(bv.y);
        bs[nc+j*4+2][kr] = f2bf(bv.z);
        bs[nc+j*4+3][kr] = f2bf(bv.w);
      }
    } else {
      int nr = tid >> 2, kc = (tid & 3)*16;
      int n = n0 + nr;
      #pragma unroll
      for (int j = 0; j < 4; ++j){
        float4 bv = make_float4(0.f,0.f,0.f,0.f);
        if (n < N) bv = *(const float4*)&B[(size_t)n*K + k0 + kc + j*4];
        ushort4 u = make_ushort4(f2bf(bv.x), f2bf(bv.y), f2bf(bv.z), f2bf(bv.w));
        *(ushort4*)&bs[nr][kc + j*4] = u;
      }
    }
    __syncthreads();
    const int mr = w*16 + (l & 15);
    const int kb = (l >> 4)*8;
    #pragma unroll
    for (int kc2 = 0; kc2 < 2; ++kc2){
      bf16x8 af = *(const bf16x8*)&as[mr][kc2*32 + kb];
      #pragma unroll
      for (int nt = 0; nt < 4; ++nt){
        bf16x8 bfr = *(const bf16x8*)&bs[nt*16 + (l & 15)][kc2*32 + kb];
        acc[nt] = __builtin_amdgcn_mfma_f32_16x16x32_bf16(af, bfr, acc[nt], 0, 0, 0);
      }
    }
    __syncthreads();
  }
  #pragma unroll
  for (int nt = 0; nt < 4; ++nt){
    int col = n0 + nt*16 + (l & 15);
    if (col < N){
      #pragma unroll
      for (int r = 0; r < 4; ++r){
        int row = m0 + w*16 + (l >> 4)*4 + r;
        C[(size_t)row*N + col] = acc[nt][r];
      }
    }
  }
}

// ---- Wout GEMM with fused comb (A = p0+p1) and resid (x += y + A@Wout) ----
__global__ void __launch_bounds__(256) k_gemm_wout(const float* __restrict__ p0,
                                                   const float* __restrict__ p1,
                                                   const float* __restrict__ B,
                                                   const float* __restrict__ y,
                                                   float* __restrict__ x){
  __shared__ unsigned short as[64][88];
  __shared__ unsigned short bs[64][88];
  const int tid = threadIdx.x;
  const int w = tid >> 6, l = tid & 63;
  const int m0 = blockIdx.y*64, n0 = blockIdx.x*64;
  f32x4 acc[4] = {};
  for (int k0 = 0; k0 < DD; k0 += 64){
    { int ar = tid >> 2, ac = (tid & 3)*16;
      #pragma unroll
      for (int j = 0; j < 4; ++j){
        size_t off = (size_t)(m0+ar)*DD + k0 + ac + j*4;
        float4 a = *(const float4*)&p0[off];
        float4 b = *(const float4*)&p1[off];
        a.x += b.x; a.y += b.y; a.z += b.z; a.w += b.w;
        ushort4 u = make_ushort4(f2bf(a.x), f2bf(a.y), f2bf(a.z), f2bf(a.w));
        *(ushort4*)&as[ar][ac + j*4] = u;
      }
    }
    { int kr = tid >> 2, nc = (tid & 3)*16;
      #pragma unroll
      for (int j = 0; j < 4; ++j){
        float4 bv = *(const float4*)&B[(size_t)(k0+kr)*DD + n0 + nc + j*4];
        bs[nc+j*4+0][kr] = f2bf(bv.x);
        bs[nc+j*4+1][kr] = f2bf(bv.y);
        bs[nc+j*4+2][kr] = f2bf(bv.z);
        bs[nc+j*4+3][kr] = f2bf(bv.w);
      }
    }
    __syncthreads();
    const int mr = w*16 + (l & 15);
    const int kb = (l >> 4)*8;
    #pragma unroll
    for (int kc2 = 0; kc2 < 2; ++kc2){
      bf16x8 af = *(const bf16x8*)&as[mr][kc2*32 + kb];
      #pragma unroll
      for (int nt = 0; nt < 4; ++nt){
        bf16x8 bfr = *(const bf16x8*)&bs[nt*16 + (l & 15)][kc2*32 + kb];
        acc[nt] = __builtin_amdgcn_mfma_f32_16x16x32_bf16(af, bfr, acc[nt], 0, 0, 0);
      }
    }
    __syncthreads();
  }
  #pragma unroll
  for (int nt = 0; nt < 4; ++nt){
    int col = n0 + nt*16 + (l & 15);
    #pragma unroll
    for (int r = 0; r < 4; ++r){
      int row = m0 + w*16 + (l >> 4)*4 + r;
      size_t off = (size_t)row*DD + col;
      x[off] = x[off] + y[off] + acc[nt][r];
    }
  }
}

// ---------------- f32 GEMM (small-N path, proj only) ----------------
template<bool BT>
__global__ void __launch_bounds__(128) k_gemm(const float* __restrict__ A,
                                              const float* __restrict__ B,
                                              float* __restrict__ C, int N, int K){
  __shared__ float as[16][68];
  __shared__ float bs[16][68];
  const int tid = threadIdx.x;
  const int tx = tid & 15, ty = tid >> 4;
  const int m0 = blockIdx.y * 64, n0 = blockIdx.x * 64;
  float acc[8][4] = {};
  for (int k0 = 0; k0 < K; k0 += 16){
    #pragma unroll
    for (int r = 0; r < 2; ++r){
      int idx = tid + r*128;
      int mm = idx >> 2, kk4 = (idx & 3) * 4;
      float4 a = *(const float4*)&A[(size_t)(m0+mm)*K + k0 + kk4];
      as[kk4+0][mm] = a.x; as[kk4+1][mm] = a.y; as[kk4+2][mm] = a.z; as[kk4+3][mm] = a.w;
    }
    if (!BT){
      #pragma unroll
      for (int r = 0; r < 2; ++r){
        int idx = tid + r*128;
        int kk = idx >> 4, nn4 = (idx & 15) * 4;
        int n = n0 + nn4;
        float4 b = make_float4(0.f,0.f,0.f,0.f);
        if (n < N) b = *(const float4*)&B[(size_t)(k0+kk)*N + n];
        *(float4*)&bs[kk][nn4] = b;
      }
    } else {
      int nn = tid >> 1, kk8 = (tid & 1) * 8;
      int n = n0 + nn;
      float4 b0 = make_float4(0.f,0.f,0.f,0.f), b1 = b0;
      if (n < N){
        b0 = *(const float4*)&B[(size_t)n*K + k0 + kk8];
        b1 = *(const float4*)&B[(size_t)n*K + k0 + kk8 + 4];
      }
      bs[kk8+0][nn]=b0.x; bs[kk8+1][nn]=b0.y; bs[kk8+2][nn]=b0.z; bs[kk8+3][nn]=b0.w;
      bs[kk8+4][nn]=b1.x; bs[kk8+5][nn]=b1.y; bs[kk8+6][nn]=b1.z; bs[kk8+7][nn]=b1.w;
    }
    __syncthreads();
    #pragma unroll
    for (int kk = 0; kk < 16; ++kk){
      float ar[8], br[4];
      *(float4*)&ar[0] = *(const float4*)&as[kk][ty*4];
      *(float4*)&ar[4] = *(const float4*)&as[kk][32+ty*4];
      *(float4*)&br[0] = *(const float4*)&bs[kk][tx*4];
      #pragma unroll
      for (int i = 0; i < 8; ++i)
        #pragma unroll
        for (int j = 0; j < 4; ++j) acc[i][j] = fmaf(ar[i], br[j], acc[i][j]);
    }
    __syncthreads();
  }
  int n = n0 + tx*4;
  if (n < N){
    #pragma unroll
    for (int i = 0; i < 8; ++i){
      int row = m0 + ((i < 4) ? (ty*4 + i) : (32 + ty*4 + i - 4));
      float4 r; r.x=acc[i][0]; r.y=acc[i][1]; r.z=acc[i][2]; r.w=acc[i][3];
      *(float4*)&C[(size_t)row*N + n] = r;
    }
  }
}

// ---------------- causal depthwise conv + silu gating --------
__global__ void k_conv(const float* __restrict__ u, const float* __restrict__ g,
                       const float* __restrict__ cw, const float* __restrict__ cb,
                       float* __restrict__ hh){
  int idx = blockIdx.x*256 + threadIdx.x;
  int c  = idx % DIM;
  int bt = idx / DIM;
  int t  = bt % TT;
  float acc = cb[c];
  #pragma unroll
  for (int j = 0; j < KW; ++j){
    int dt_ = j - (KW-1);
    if (t + dt_ >= 0) acc = fmaf(u[(bt + dt_)*DIM + c], cw[c*KW + j], acc);
  }
  float h = siluf(acc);
  hh[idx] = siluf(g[idx]) * h;
}

// ---------------- pack small projection weights into (D, 28) ----------------
__global__ void k_pack(const float* __restrict__ Wg, const float* __restrict__ Wb,
                       const float* __restrict__ Wa, const float* __restrict__ Wbl,
                       float* __restrict__ Wp){
  int d = blockIdx.x;
  int j = threadIdx.x;
  if (j >= 28) return;
  float v;
  if (j < 4)        v = Wg[d*HH + j];
  else if (j < 12){ int m=(j-4)>>2, h=(j-4)&3;  v = Wb[(m*DD + d)*HH + h]; }
  else if (j < 20){ int m=(j-12)>>2, h=(j-12)&3; v = Wa[(m*DD + d)*HH + h]; }
  else              v = Wbl[d*(HH*MM) + (j-20)];
  Wp[d*28 + j] = v;
}

// ---------------- rk normalization ----------
__global__ void k_rk(const float* __restrict__ y, float* __restrict__ rkb){
  int blk = blockIdx.x;
  int lane = threadIdx.x;
  int row = blk >> 2, h = blk & 3;
  float v = y[row*DD + h*HDIM + lane];
  float ss = v*v;
  #pragma unroll
  for (int o = 32; o > 0; o >>= 1) ss += __shfl_xor(ss, o, 64);
  float nrm = fmaxf(sqrtf(ss), 1e-12f);
  rkb[row*DD + h*HDIM + lane] = v / nrm;
}

// ---------------- precompute scan scalars ----------
__global__ void k_scal(const float* __restrict__ proj, const float* __restrict__ A_log,
                       const float* __restrict__ dtb, float* __restrict__ scal){
  int i = blockIdx.x*256 + threadIdx.x;
  int mh = i & 7;
  int row = i >> 3;
  int m = mh >> 2, h = mh & 3;
  const float* pv = proj + (size_t)row*28;
  float gs  = sigf(pv[h]);
  float btv = sigf(pv[4 + m*4 + h]);
  float sp  = pv[12 + m*4 + h] + dtb[m*HH + h];
  sp = (sp > 15.f) ? sp : log1pf(__expf(sp));
  float dc  = __expf(-__expf(A_log[m*HH + h]) * sp);
  float l0 = pv[20 + h*2], l1 = pv[20 + h*2 + 1];
  float mx = fmaxf(l0, l1);
  float e0 = __expf(l0-mx), e1 = __expf(l1-mx);
  float bl = (m ? e1 : e0) / (e0 + e1);
  float4 o; o.x = dc; o.y = btv; o.z = bl*gs; o.w = 0.f;
  *(float4*)&scal[((size_t)row*MM + m)*(HH*4) + h*4] = o;
}

// ---------------- sequential delta-memory scan ----------
// grid = B*H*M*8 blocks (k-split by 8), 64 threads = 1 wave.
// Lane bits {0,1,3} = d-octant q (8 d each, S[8]/lane); bits {2,4,5} = k (8/block).
// d-reduce = xor1 + xor2 + xor8, all DPP (quad_perm / row_ror:8) — no DS ops.
// Depth-2 register prefetch, issued at step START (PF buffer dead there).

#define SSTEP(T_, WK, RK, PF, VB, SB) { \
  const float dc = SB.x, btv = SB.y, blg = SB.z; \
  const float v = VB; \
  { const int tn_ = ((T_)+2 < 64) ? (T_)+2 : 63; \
    PF[0] = *(const float4*)&s_rk[p][tn_][dbase + 0]; \
    PF[1] = *(const float4*)&s_rk[p][tn_][dbase + 4]; \
    VB = s_v[p][tn_][klocal]; \
    SB = *(const float4*)&s_sc[p][tn_][0]; } \
  float pp0=0.f,pp1=0.f; \
  { const float4 r0 = WK[0], r1 = WK[1]; \
    if (ROT == 0){ \
      pp0 = fmaf(S[0], r0.x, pp0); pp0 = fmaf(S[1], r0.y, pp0); \
      pp0 = fmaf(S[2], r0.z, pp0); pp0 = fmaf(S[3], r0.w, pp0); \
      pp1 = fmaf(S[4], r1.x, pp1); pp1 = fmaf(S[5], r1.y, pp1); \
      pp1 = fmaf(S[6], r1.z, pp1); pp1 = fmaf(S[7], r1.w, pp1); \
    } else { \
      pp0 = fmaf(S[0], -r0.y, pp0); pp0 = fmaf(S[1], r0.x, pp0); \
      pp0 = fmaf(S[2], -r0.w, pp0); pp0 = fmaf(S[3], r0.z, pp0); \
      pp1 = fmaf(S[4], -r1.y, pp1); pp1 = fmaf(S[5], r1.x, pp1); \
      pp1 = fmaf(S[6], -r1.w, pp1); pp1 = fmaf(S[7], r1.z, pp1); } } \
  float pp = pp0 + pp1; \
  pp = xor1_add(pp); pp = xor2_add(pp); pp = xor8_add(pp); \
  const float err = (v - dc*pp)*btv; \
  float rr0=0.f,rr1=0.f; \
  _Pragma("unroll") \
  for (int j = 0; j < 2; ++j){ const float4 rp = WK[j]; const float4 rc = RK[j]; \
    float w0,w1,w2,w3,c0,c1,c2,c3; \
    if (ROT == 0){ w0=rp.x; w1=rp.y; w2=rp.z; w3=rp.w; c0=rc.x; c1=rc.y; c2=rc.z; c3=rc.w; } \
    else { w0=-rp.y; w1=rp.x; w2=-rp.w; w3=rp.z; c0=-rc.y; c1=rc.x; c2=-rc.w; c3=rc.z; } \
    S[4*j+0] = fmaf(S[4*j+0], dc, w0*err); rr0 = fmaf(S[4*j+0], c0, rr0); \
    S[4*j+1] = fmaf(S[4*j+1], dc, w1*err); rr1 = fmaf(S[4*j+1], c1, rr1); \
    S[4*j+2] = fmaf(S[4*j+2], dc, w2*err); rr0 = fmaf(S[4*j+2], c2, rr0); \
    S[4*j+3] = fmaf(S[4*j+3], dc, w3*err); rr1 = fmaf(S[4*j+3], c3, rr1); } \
  float rr = rr0 + rr1; \
  rr = xor1_add(rr); rr = xor2_add(rr); rr = xor8_add(rr); \
  if (q == 0) part[(size_t)(rowchunk + (T_))*DD + h*HDIM + kq*8 + klocal] = blg*rr; \
}

template<int ROT>
__device__ __forceinline__ void scan_body(int b, int h, int kq, int l,
    const float* __restrict__ vals, const float* __restrict__ rkb,
    const float* __restrict__ scal, float* __restrict__ part,
    float (*s_rk)[64][64], float (*s_v)[64][8], float (*s_sc)[64][4])
{
  const int q = (l & 3) | ((l & 8) >> 1);          // bits 0,1,3
  const int klocal = ((l >> 2) & 1) | ((l >> 3) & 6); // bits 2,4,5
  const int dbase = q*8;
  const int rowbase = b*TT;

  float S[8];
  #pragma unroll
  for (int j = 0; j < 8; ++j) S[j] = 0.f;
  float4 rb0[2], rb1[2], rb2[2], rb3[2];
  #pragma unroll
  for (int j = 0; j < 2; ++j){
    rb0[j]=make_float4(0.f,0.f,0.f,0.f); rb1[j]=rb0[j]; rb2[j]=rb0[j]; rb3[j]=rb0[j];
  }

  auto stage = [&](int c, int pbuf){
    const int r0 = rowbase + c*64;
    #pragma unroll
    for (int i = 0; i < 16; ++i){
      const float* g = rkb + (size_t)(r0 + i*4 + (l>>4))*DD + h*HDIM + (l&15)*4;
      gl_lds16(g, &s_rk[pbuf][i*4][0]);
    }
    #pragma unroll
    for (int i = 0; i < 2; ++i){
      const float* g = vals + ((size_t)(r0 + i*32 + (l>>1))*MM + ROT)*DD + h*HDIM + kq*8 + (l&1)*4;
      gl_lds16(g, &s_v[pbuf][i*32][0]);
    }
    { const float* g = scal + ((size_t)(r0 + l)*MM + ROT)*(HH*4) + h*4;
      gl_lds16(g, &s_sc[pbuf][0][0]); }
  };

  stage(0, 0);
  float vb0 = 0.f, vb1 = 0.f;
  float4 sb0 = make_float4(0.f,0.f,0.f,0.f), sb1 = sb0;
  for (int c = 0; c < TT/64; ++c){
    const int p = c & 1;
    __syncthreads();                 // vmcnt drain: chunk c staged
    if (c + 1 < TT/64) stage(c+1, p^1);
    #pragma unroll
    for (int j = 0; j < 2; ++j) rb0[j] = *(const float4*)&s_rk[p][0][dbase + 4*j];
    #pragma unroll
    for (int j = 0; j < 2; ++j) rb1[j] = *(const float4*)&s_rk[p][1][dbase + 4*j];
    vb0 = s_v[p][0][klocal]; vb1 = s_v[p][1][klocal];
    sb0 = *(const float4*)&s_sc[p][0][0]; sb1 = *(const float4*)&s_sc[p][1][0];
    const int rowchunk = rowbase + c*64;
    for (int tt = 0; tt < 64; tt += 4){
      SSTEP(tt,   rb3, rb0, rb2, vb0, sb0)
      SSTEP(tt+1, rb0, rb1, rb3, vb1, sb1)
      SSTEP(tt+2, rb1, rb2, rb0, vb0, sb0)
      SSTEP(tt+3, rb2, rb3, rb1, vb1, sb1)
    }
  }
}

__global__ void __launch_bounds__(64) k_scan(const float* __restrict__ vals,
                                             const float* __restrict__ rkb,
                                             const float* __restrict__ scal,
                                             float* __restrict__ partials){
  __shared__ float s_rk[2][64][64];
  __shared__ float s_v [2][64][8];
  __shared__ float s_sc[2][64][4];
  const int bi = blockIdx.x;      // (((b*HH)+h)*MM + m)*8 + kq
  const int kq = bi & 7;
  const int m  = (bi >> 3) & 1;
  const int h  = (bi >> 4) & 3;
  const int b  = bi >> 6;
  float* part = partials + (size_t)m*(BB*TT*DD);
  if (m == 0) scan_body<0>(b, h, kq, threadIdx.x, vals, rkb, scal, part, s_rk, s_v, s_sc);
  else        scan_body<1>(b, h, kq, threadIdx.x, vals, rkb, scal, part, s_rk, s_v, s_sc);
}

extern "C" void kernel_launch(void* const* d_in, const int* in_sizes, int n_in,
                              void* d_out, int out_size, void* d_ws, size_t ws_size,
                              hipStream_t stream){
  const int*   ids   = (const int*)d_in[0];
  const float* emb   = (const float*)d_in[1];
  const float* normw = (const float*)d_in[2];
  const float* Wup   = (const float*)d_in[3];
  const float* Wgate = (const float*)d_in[4];
  const float* Wdown = (const float*)d_in[5];
  const float* convw = (const float*)d_in[6];
  const float* convb = (const float*)d_in[7];
  const float* Wv    = (const float*)d_in[8];
  const float* Wg    = (const float*)d_in[9];
  const float* Wb    = (const float*)d_in[10];
  const float* Wa    = (const float*)d_in[11];
  const float* A_log = (const float*)d_in[12];
  const float* dtb   = (const float*)d_in[13];
  const float* Wbl   = (const float*)d_in[14];
  const float* Wout  = (const float*)d_in[15];
  const float* fnw   = (const float*)d_in[16];
  float* out = (float*)d_out;

  const int ROWS = BB*TT;              // 4096
  const size_t MEG = 1u << 20;
  float* ws   = (float*)d_ws;
  float* x    = ws;                    // 1M
  float* nx   = x    + MEG;            // 1M
  float* big1 = nx   + MEG;            // 2M : u, then vals
  float* big2 = big1 + 2*MEG;          // 2M : g/hh, then partials
  float* y    = big2 + 2*MEG;          // 1M
  float* proj = y    + MEG;            // 128K
  float* rkb  = proj + (1u<<17);       // 1M
  float* Wp   = rkb  + MEG;            // 8K
  float* scal = Wp   + 8192;           // 128K

  k_embed<<<ROWS, DD, 0, stream>>>(ids, emb, x);

  for (int l = 0; l < LL; ++l){
    k_rmsnorm<<<ROWS, 64, 0, stream>>>(x, normw + l*DD, nx);
    float* u = big1; float* g = big2;
    k_gemm_bf<false><<<dim3(DIM/64, ROWS/64), 256, 0, stream>>>(nx, Wup + (size_t)l*DD*DIM, u, DIM, DD);
    k_gemm_bf<false><<<dim3(DIM/64, ROWS/64), 256, 0, stream>>>(nx, Wgate + (size_t)l*DD*DIM, g, DIM, DD);
    k_conv<<<(ROWS*DIM)/256, 256, 0, stream>>>(u, g, convw + l*DIM*KW, convb + l*DIM, g);
    k_gemm_bf<false><<<dim3(DD/64, ROWS/64), 256, 0, stream>>>(g, Wdown + (size_t)l*DIM*DD, y, DD, DIM);
    float* vals = big1;
    k_gemm_bf<false><<<dim3((MM*DD)/64, ROWS/64), 256, 0, stream>>>(y, Wv + (size_t)l*DD*MM*DD, vals, MM*DD, DD);
    k_pack<<<DD, 32, 0, stream>>>(Wg + l*DD*HH, Wb + l*MM*DD*HH, Wa + l*MM*DD*HH,
                                  Wbl + l*DD*HH*MM, Wp);
    k_gemm<false><<<dim3(1, ROWS/64), 128, 0, stream>>>(y, Wp, proj, 28, DD);
    k_scal<<<(ROWS*MM*HH)/256, 256, 0, stream>>>(proj, A_log + l*MM*HH, dtb + l*MM*HH, scal);
    k_rk<<<ROWS*HH, 64, 0, stream>>>(y, rkb);
    k_scan<<<BB*HH*MM*8, 64, 0, stream>>>(vals, rkb, scal, big2);
    // fused: x += y + (p0+p1)@Wout
    k_gemm_wout<<<dim3(DD/64, ROWS/64), 256, 0, stream>>>(big2, big2 + MEG,
                                                          Wout + (size_t)l*DD*DD, y, x);
  }

  k_rmsnorm<<<ROWS, 64, 0, stream>>>(x, fnw, nx);
  k_gemm_bf<true><<<dim3((VV+63)/64, ROWS/64), 256, 0, stream>>>(nx, emb, out, VV, DD);
}